// Round 22
// baseline (799.203 us; speedup 1.0000x reference)
//
#include <hip/hip_runtime.h>
#include <hip/hip_bf16.h>

// B=8 S=1024 C=512 V=512 D=512 NC=512 NF=2 H=8 TAU=1
// d_out FLOAT32: [logp 4194304][z 1048576][diff 1][ids 2048]
// Pre-LN encoder + decoder: bf16 MFMA. Post-LN z_e path (LN/ds/e2q/VQ): fp32.
// r22: fp32 gemm_k tile 64x32 (micro 4x2) -> 2x grid blocks; bit-exact k-order.

static constexpr size_t SLOT = 4194304; // 8192*512 floats

typedef short bf16x8 __attribute__((ext_vector_type(8)));
typedef float f32x4  __attribute__((ext_vector_type(4)));

__device__ __forceinline__ float eluf(float x) { return x > 0.f ? x : expm1f(x); }
__device__ __forceinline__ short f2bf(float v) {
  unsigned u = __float_as_uint(v);
  return (short)((u + 0x7FFFu + ((u >> 16) & 1u)) >> 16);
}
__device__ __forceinline__ float bf2f(short s) {
  return __uint_as_float(((unsigned)(unsigned short)s) << 16);
}

// ---------------- fp32 GEMM 64x32 (micro 4x2; f4/f2 staging + prefetch; nseg=3
// fuses k3 conv with exact rounding: r1=(s0)+bias; r2=s1+r1; r3=s2+r2) ----
__global__ __launch_bounds__(256) void gemm_k(
    const float* __restrict__ A, const float* __restrict__ W,
    const float* __restrict__ bias, const float* __restrict__ res,
    float* __restrict__ Y, int P, int K, int O,
    int act, int accum, int smod, int shift, int ystride, int yoff,
    int WS, int nseg)
{
  __shared__ alignas(16) float As[16][68];
  __shared__ alignas(16) float Bs[16][36];
  const int tid = threadIdx.x;
  const int bp = blockIdx.x * 64, bo = blockIdx.y * 32;
  const int tx = tid & 15, ty = tid >> 4;
  const int srow = tid >> 2, skq = (tid & 3) << 2;   // A staging: 64 rows x 4k
  const int brow = tid >> 3, bkq = (tid & 7) << 1;   // B staging: 32 rows x 2k
  float vout[4][2];

  for (int seg = 0; seg < nseg; seg++) {
    const int sh = (nseg == 3) ? (seg - 1) : shift;
    const float* Wseg = (nseg == 3) ? (W + (size_t)seg * 262144) : W;
    float acc[4][2];
#pragma unroll
    for (int i = 0; i < 4; i++) { acc[i][0] = 0.f; acc[i][1] = 0.f; }

    bool aok = true;
    if (smod) { const int s = (bp + srow) & (smod - 1); aok = ((unsigned)(s + sh) < (unsigned)smod); }
    const float* arow = A + (size_t)(bp + srow + sh) * K;
    const float* brw  = Wseg + (size_t)(bo + brow) * WS;

    float4 pa = aok ? *(const float4*)&arow[skq] : make_float4(0.f, 0.f, 0.f, 0.f);
    float2 pb = *(const float2*)&brw[bkq];

    for (int k0 = 0; k0 < K; k0 += 16) {
      if (act) { pa.x = eluf(pa.x); pa.y = eluf(pa.y); pa.z = eluf(pa.z); pa.w = eluf(pa.w); }
      __syncthreads();
      As[skq + 0][srow] = pa.x; As[skq + 1][srow] = pa.y;
      As[skq + 2][srow] = pa.z; As[skq + 3][srow] = pa.w;
      Bs[bkq + 0][brow] = pb.x; Bs[bkq + 1][brow] = pb.y;
      __syncthreads();
      const int kna = (k0 + 16 < K) ? (k0 + 16 + skq) : (k0 + skq);
      const int knb = (k0 + 16 < K) ? (k0 + 16 + bkq) : (k0 + bkq);
      pa = aok ? *(const float4*)&arow[kna] : make_float4(0.f, 0.f, 0.f, 0.f);
      pb = *(const float2*)&brw[knb];
#pragma unroll
      for (int kk2 = 0; kk2 < 16; kk2++) {
        const float4 av = *(const float4*)&As[kk2][ty * 4];
        const float2 bv = *(const float2*)&Bs[kk2][tx * 2];
        const float a_[4] = {av.x, av.y, av.z, av.w};
#pragma unroll
        for (int i = 0; i < 4; i++) {
          acc[i][0] += a_[i] * bv.x;
          acc[i][1] += a_[i] * bv.y;
        }
      }
    }
    if (seg == 0) {
#pragma unroll
      for (int i = 0; i < 4; i++)
#pragma unroll
        for (int j = 0; j < 2; j++) {
          float t = acc[i][j];
          if (nseg == 3 && bias) t += bias[bo + tx * 2 + j];
          vout[i][j] = t;
        }
    } else {
#pragma unroll
      for (int i = 0; i < 4; i++)
#pragma unroll
        for (int j = 0; j < 2; j++) vout[i][j] = acc[i][j] + vout[i][j];
    }
  }
#pragma unroll
  for (int i = 0; i < 4; i++) {
    const int p = bp + ty * 4 + i;
    const size_t yrow = (size_t)p * ystride + yoff;
#pragma unroll
    for (int j = 0; j < 2; j++) {
      const int o = bo + tx * 2 + j;
      float v = vout[i][j];
      if (nseg == 1) {
        if (bias) v += bias[o];
        if (res)  v += res[(size_t)p * O + o];
        if (accum) v += Y[yrow * O + o];
      }
      Y[yrow * O + o] = v;
    }
  }
}

static inline void launch_gemm(hipStream_t st, const float* A, const float* W,
                               const float* bias, const float* res, float* Y,
                               int P, int K, int O, int act, int accum,
                               int smod, int shift, int ystride, int yoff,
                               int WS, int nseg)
{
  dim3 g(P / 64, O / 32);
  gemm_k<<<g, 256, 0, st>>>(A, W, bias, res, Y, P, K, O, act, accum, smod, shift,
                            ystride, yoff, WS, nseg);
}

// ---------------- bf16 MFMA GEMM (K=512; k3 fused conv; Y/Yb nullable) ----
__global__ __launch_bounds__(256) void bgemm_k(
    const short* __restrict__ A, const short* __restrict__ W,
    const float* __restrict__ bias, const float* __restrict__ res,
    float* __restrict__ Y, int P, int O, int accum,
    int smod, int shift, int ystride, int yoff,
    short* __restrict__ Yb, int bact, int k3)
{
  __shared__ short As[4096];
  __shared__ short Bs[4096];
  const int tid = threadIdx.x;
  const int lane = tid & 63, wid = tid >> 6;
  const int wr = wid >> 1, wc = wid & 1;
  const int bp = blockIdx.x * 64, bo = blockIdx.y * 64;
  f32x4 acc[2][2];
#pragma unroll
  for (int mi = 0; mi < 2; mi++)
#pragma unroll
    for (int ni = 0; ni < 2; ni++) acc[mi][ni] = (f32x4){0.f, 0.f, 0.f, 0.f};

  const int nseg = k3 ? 3 : 1;
  for (int seg = 0; seg < nseg; seg++) {
    const int sh = k3 ? (seg - 1) : shift;
    const int sm = k3 ? 256 : smod;
    const short* Wseg = W + (size_t)seg * 262144;
    for (int k0 = 0; k0 < 512; k0 += 64) {
#pragma unroll
      for (int c0 = 0; c0 < 2; c0++) {
        const int c = tid + c0 * 256;
        const int row = c >> 3, kc = c & 7;
        int soff = (row << 6) + (kc << 3); soff ^= (row & 7) << 3;
        const int p = bp + row;
        bf16x8 av = {0, 0, 0, 0, 0, 0, 0, 0};
        bool ok = true;
        if (sm) { const int s = p & (sm - 1); ok = ((unsigned)(s + sh) < (unsigned)sm); }
        if (ok) av = *(const bf16x8*)&A[(size_t)(p + sh) * 512 + k0 + (kc << 3)];
        *(bf16x8*)&As[soff] = av;
        *(bf16x8*)&Bs[soff] = *(const bf16x8*)&Wseg[(size_t)(bo + row) * 512 + k0 + (kc << 3)];
      }
      __syncthreads();
#pragma unroll
      for (int ks = 0; ks < 2; ks++) {
        bf16x8 af[2], bfr[2];
#pragma unroll
        for (int mi = 0; mi < 2; mi++) {
          const int row = wr * 32 + mi * 16 + (lane & 15);
          int soff = (row << 6) + (ks << 5) + ((lane >> 4) << 3);
          soff ^= (row & 7) << 3;
          af[mi] = *(const bf16x8*)&As[soff];
        }
#pragma unroll
        for (int ni = 0; ni < 2; ni++) {
          const int row = wc * 32 + ni * 16 + (lane & 15);
          int soff = (row << 6) + (ks << 5) + ((lane >> 4) << 3);
          soff ^= (row & 7) << 3;
          bfr[ni] = *(const bf16x8*)&Bs[soff];
        }
#pragma unroll
        for (int mi = 0; mi < 2; mi++)
#pragma unroll
          for (int ni = 0; ni < 2; ni++)
            acc[mi][ni] = __builtin_amdgcn_mfma_f32_16x16x32_bf16(af[mi], bfr[ni], acc[mi][ni], 0, 0, 0);
      }
      __syncthreads();
    }
  }
#pragma unroll
  for (int mi = 0; mi < 2; mi++)
#pragma unroll
    for (int ni = 0; ni < 2; ni++)
#pragma unroll
      for (int r = 0; r < 4; r++) {
        const int p = bp + wr * 32 + mi * 16 + ((lane >> 4) << 2) + r;
        const int o = bo + wc * 32 + ni * 16 + (lane & 15);
        float v = acc[mi][ni][r];
        if (bias) v += bias[o];
        if (res)  v += res[(size_t)p * O + o];
        const size_t yi = ((size_t)p * ystride + yoff) * O + o;
        if (accum) v += Y[yi];
        if (Y) Y[yi] = v;
        if (Yb) Yb[yi] = f2bf(bact ? eluf(v) : v);
      }
}

// ---------------- bf16 MFMA flash attention, QBLK=128, 512 threads ----
__global__ __launch_bounds__(512) void battn_k(
    const short* __restrict__ qkv, float* __restrict__ Oa,
    short* __restrict__ Ob, int S)
{
  __shared__ short sq[8192];
  __shared__ short sk[4096];
  __shared__ short svt[4096];
  const int tid = threadIdx.x;
  const int lane = tid & 63, w = tid >> 6;
  const int bl = blockIdx.y >> 3, h = blockIdx.y & 7;
  const int q0 = blockIdx.x * 128;
  const short* base = qkv + (size_t)bl * S * 1536 + h * 64;

  {
    const int row = tid >> 2, c0 = (tid & 3) << 4;
    const short* src = base + (size_t)(q0 + row) * 1536 + c0;
    bf16x8 v0 = *(const bf16x8*)&src[0];
    bf16x8 v1 = *(const bf16x8*)&src[8];
#pragma unroll
    for (int e = 0; e < 8; e++) {
      v0[e] = f2bf(bf2f(v0[e]) * 0.125f);
      v1[e] = f2bf(bf2f(v1[e]) * 0.125f);
    }
    int s0 = (row << 6) + c0;       s0 ^= (row & 7) << 3;
    int s1 = (row << 6) + c0 + 8;   s1 ^= (row & 7) << 3;
    *(bf16x8*)&sq[s0] = v0; *(bf16x8*)&sq[s1] = v1;
  }
  __syncthreads();
  bf16x8 af[2];
#pragma unroll
  for (int ks = 0; ks < 2; ks++) {
    const int row = (w << 4) + (lane & 15);
    int soff = (row << 6) + (((lane >> 4) + 4 * ks) << 3);
    soff ^= (row & 7) << 3;
    af[ks] = *(const bf16x8*)&sq[soff];
  }

  f32x4 oacc[4];
#pragma unroll
  for (int dt = 0; dt < 4; dt++) oacc[dt] = (f32x4){0.f, 0.f, 0.f, 0.f};
  float m[4], l[4];
#pragma unroll
  for (int r = 0; r < 4; r++) { m[r] = -INFINITY; l[r] = 0.f; }

  for (int t0 = 0; t0 < S; t0 += 64) {
    __syncthreads();
    if (tid < 256) {
      const int row = tid >> 2, c0 = (tid & 3) << 4;
      const short* ksrc = base + (size_t)(t0 + row) * 1536 + 512 + c0;
      int s0 = (row << 6) + c0;       s0 ^= (row & 7) << 3;
      int s1 = (row << 6) + c0 + 8;   s1 ^= (row & 7) << 3;
      *(bf16x8*)&sk[s0] = *(const bf16x8*)&ksrc[0];
      *(bf16x8*)&sk[s1] = *(const bf16x8*)&ksrc[8];
    } else {
      const int t = tid - 256;
      const int row = t >> 2, c0 = (t & 3) << 4;
      const short* vsrc = base + (size_t)(t0 + row) * 1536 + 1024 + c0;
      const bf16x8 va0 = *(const bf16x8*)&vsrc[0];
      const bf16x8 va1 = *(const bf16x8*)&vsrc[8];
#pragma unroll
      for (int i = 0; i < 16; i++) {
        const int dd = c0 + i;
        int so = (dd << 6) + row;
        so ^= ((dd & 7) ^ (((dd >> 4) & 3) << 1)) << 3;
        svt[so] = (i < 8) ? va0[i & 7] : va1[i & 7];
      }
    }
    __syncthreads();
    f32x4 sacc[4];
#pragma unroll
    for (int ct = 0; ct < 4; ct++) {
      sacc[ct] = (f32x4){0.f, 0.f, 0.f, 0.f};
#pragma unroll
      for (int ks = 0; ks < 2; ks++) {
        const int row = (ct << 4) + (lane & 15);
        int soff = (row << 6) + (((lane >> 4) + 4 * ks) << 3);
        soff ^= (row & 7) << 3;
        const bf16x8 bk = *(const bf16x8*)&sk[soff];
        sacc[ct] = __builtin_amdgcn_mfma_f32_16x16x32_bf16(af[ks], bk, sacc[ct], 0, 0, 0);
      }
    }
    float p[4][4]; float corr[4];
#pragma unroll
    for (int r = 0; r < 4; r++) {
      float mx = fmaxf(fmaxf(sacc[0][r], sacc[1][r]), fmaxf(sacc[2][r], sacc[3][r]));
      mx = fmaxf(mx, __shfl_xor(mx, 1));
      mx = fmaxf(mx, __shfl_xor(mx, 2));
      mx = fmaxf(mx, __shfl_xor(mx, 4));
      mx = fmaxf(mx, __shfl_xor(mx, 8));
      const float newm = fmaxf(m[r], mx);
      corr[r] = expf(m[r] - newm);
      float psum = 0.f;
#pragma unroll
      for (int ct = 0; ct < 4; ct++) { p[ct][r] = expf(sacc[ct][r] - newm); psum += p[ct][r]; }
      psum += __shfl_xor(psum, 1);
      psum += __shfl_xor(psum, 2);
      psum += __shfl_xor(psum, 4);
      psum += __shfl_xor(psum, 8);
      l[r] = l[r] * corr[r] + psum;
      m[r] = newm;
#pragma unroll
      for (int dt = 0; dt < 4; dt++) oacc[dt][r] *= corr[r];
    }
#pragma unroll
    for (int r = 0; r < 4; r++)
#pragma unroll
      for (int ct = 0; ct < 4; ct++) {
        const int q = (w << 4) + ((lane >> 4) << 2) + r;
        const int kv = (ct << 4) + (lane & 15);
        int so = (q << 6) + kv; so ^= (q & 7) << 3;
        sq[so] = f2bf(p[ct][r]);
      }
#pragma unroll
    for (int ks = 0; ks < 2; ks++) {
      const int prow = (w << 4) + (lane & 15);
      int poff = (prow << 6) + (((lane >> 4) + 4 * ks) << 3);
      poff ^= (prow & 7) << 3;
      const bf16x8 pa = *(const bf16x8*)&sq[poff];
#pragma unroll
      for (int dt = 0; dt < 4; dt++) {
        const int vrow = (dt << 4) + (lane & 15);
        int voff = (vrow << 6) + (((lane >> 4) + 4 * ks) << 3);
        voff ^= ((vrow & 7) ^ (((vrow >> 4) & 3) << 1)) << 3;
        const bf16x8 bv = *(const bf16x8*)&svt[voff];
        oacc[dt] = __builtin_amdgcn_mfma_f32_16x16x32_bf16(pa, bv, oacc[dt], 0, 0, 0);
      }
    }
  }
#pragma unroll
  for (int r = 0; r < 4; r++) {
    const float inv = 1.f / l[r];
    const int q = (w << 4) + ((lane >> 4) << 2) + r;
    const size_t rowbase = (size_t)(bl * S + q0 + q) * 512 + h * 64;
#pragma unroll
    for (int dt = 0; dt < 4; dt++) {
      const int d = (dt << 4) + (lane & 15);
      const float ov = oacc[dt][r] * inv;
      if (Oa) Oa[rowbase + d] = ov;
      if (Ob) Ob[rowbase + d] = f2bf(ov);
    }
  }
}

// ---------------- fp32 -> bf16 cast (weights)
__global__ __launch_bounds__(256) void cast_k(const float* __restrict__ src,
    short* __restrict__ dst, int act)
{
  const size_t i = ((size_t)blockIdx.x * 256 + threadIdx.x) * 8;
  float4 a = *(const float4*)&src[i];
  float4 b = *(const float4*)&src[i + 4];
  if (act) {
    a.x = eluf(a.x); a.y = eluf(a.y); a.z = eluf(a.z); a.w = eluf(a.w);
    b.x = eluf(b.x); b.y = eluf(b.y); b.z = eluf(b.z); b.w = eluf(b.w);
  }
  bf16x8 o;
  o[0] = f2bf(a.x); o[1] = f2bf(a.y); o[2] = f2bf(a.z); o[3] = f2bf(a.w);
  o[4] = f2bf(b.x); o[5] = f2bf(b.y); o[6] = f2bf(b.z); o[7] = f2bf(b.w);
  *(bf16x8*)&dst[i] = o;
}

// q2d_w [512 o][512 k][3] -> 3 mats [512][512] bf16
__global__ __launch_bounds__(256) void q2dw_k(const float* __restrict__ src, short* __restrict__ dst)
{
  const int idx = blockIdx.x * 256 + threadIdx.x;
  const int w = idx >> 18, rem = idx & 262143;
  const int o = rem >> 9, k = rem & 511;
  dst[idx] = f2bf(src[(size_t)o * 1536 + k * 3 + w]);
}

// dec_up_w [NF][512 i][512 o][2 k] -> 4 mats [(f*2+k)][512 o][512 i] bf16
__global__ __launch_bounds__(256) void upw_k(const float* __restrict__ src, short* __restrict__ dst)
{
  const int idx = blockIdx.x * 256 + threadIdx.x;
  const int mi = idx >> 18, f = mi >> 1, kq = mi & 1;
  const int rem = idx & 262143;
  const int o = rem >> 9, i2 = rem & 511;
  dst[idx] = f2bf(src[(size_t)f * 524288 + (size_t)i2 * 1024 + o * 2 + kq]);
}

// down weight [512 o][512 i][2 ks] -> fp32 [512 o][ks*512+i]
__global__ __launch_bounds__(256) void downw_k(const float* __restrict__ src, float* __restrict__ dst)
{
  const int idx = blockIdx.x * 256 + threadIdx.x; // 524288
  const int i = idx & 511, ks = (idx >> 9) & 1, o = idx >> 10;
  dst[idx] = src[(size_t)o * 1024 + i * 2 + ks];
}

// e2q_w [512 o][512 k][3 w] -> fp32 [3 w][512 o][512 k]
__global__ __launch_bounds__(256) void e2qw_k(const float* __restrict__ src, float* __restrict__ dst)
{
  const int idx = blockIdx.x * 256 + threadIdx.x; // 786432
  const int w = idx >> 18, rem = idx & 262143;
  const int o = rem >> 9, k = rem & 511;
  dst[idx] = src[(size_t)o * 1536 + k * 3 + w];
}

// codebook [512 d][512 n] -> fp32 cbT [512 n][512 d]
__global__ __launch_bounds__(256) void cbt_k(const float* __restrict__ src, float* __restrict__ dst)
{
  const int idx = blockIdx.x * 256 + threadIdx.x; // 262144
  const int n = idx >> 9, d = idx & 511;
  dst[idx] = src[(size_t)d * 512 + n];
}

// ---------------- layernorm over C=512, optional bf16 out
__global__ __launch_bounds__(256) void ln_k(const float* __restrict__ X,
    const float* __restrict__ g, const float* __restrict__ bta,
    float* __restrict__ Y, short* __restrict__ Ob)
{
  const int row = blockIdx.x * 4 + (threadIdx.x >> 6);
  const int lane = threadIdx.x & 63;
  const float* x = X + (size_t)row * 512;
  float v[8]; float s = 0.f;
#pragma unroll
  for (int i = 0; i < 8; i++) { v[i] = x[lane + i * 64]; s += v[i]; }
#pragma unroll
  for (int off = 1; off < 64; off <<= 1) s += __shfl_xor(s, off);
  const float mean = s * (1.f / 512.f);
  float vs = 0.f;
#pragma unroll
  for (int i = 0; i < 8; i++) { const float d = v[i] - mean; vs += d * d; }
#pragma unroll
  for (int off = 1; off < 64; off <<= 1) vs += __shfl_xor(vs, off);
  const float rstd = 1.f / sqrtf(vs * (1.f / 512.f) + 1e-5f);
  float* y = Y ? (Y + (size_t)row * 512) : nullptr;
#pragma unroll
  for (int i = 0; i < 8; i++) {
    const int c = lane + i * 64;
    const float o = (v[i] - mean) * rstd * g[c] + bta[c];
    if (y) y[c] = o;
    if (Ob) Ob[(size_t)row * 512 + c] = f2bf(o);
  }
}

// ---------------- log_softmax over C=512 -> f32 out
__global__ __launch_bounds__(256) void lsm_k(const float* __restrict__ X,
    float* __restrict__ out)
{
  const int row = blockIdx.x * 4 + (threadIdx.x >> 6);
  const int lane = threadIdx.x & 63;
  const float* x = X + (size_t)row * 512;
  float v[8]; float mx = -3.0e38f;
#pragma unroll
  for (int i = 0; i < 8; i++) { v[i] = x[lane + i * 64]; mx = fmaxf(mx, v[i]); }
#pragma unroll
  for (int off = 1; off < 64; off <<= 1) mx = fmaxf(mx, __shfl_xor(mx, off));
  float sum = 0.f;
#pragma unroll
  for (int i = 0; i < 8; i++) sum += expf(v[i] - mx);
#pragma unroll
  for (int off = 1; off < 64; off <<= 1) sum += __shfl_xor(sum, off);
  const float ls = logf(sum);
  float* y = out + (size_t)row * 512;
#pragma unroll
  for (int i = 0; i < 8; i++) y[lane + i * 64] = v[i] - mx - ls;
}

// ---------------- embedding gather (+bf16 elu copy)
__global__ __launch_bounds__(256) void embed_k(const int* __restrict__ x,
    const float* __restrict__ emb, float* __restrict__ out, short* __restrict__ outb)
{
  const int i = blockIdx.x * 256 + threadIdx.x;
  const int p = i >> 7, c4 = i & 127;
  const int id = x[p];
  const float4 v = *(const float4*)&emb[(size_t)id * 512 + c4 * 4];
  *(float4*)&out[(size_t)p * 512 + c4 * 4] = v;
  short* ob = outb + (size_t)p * 512 + c4 * 4;
  ob[0] = f2bf(eluf(v.x)); ob[1] = f2bf(eluf(v.y));
  ob[2] = f2bf(eluf(v.z)); ob[3] = f2bf(eluf(v.w));
}

// ---------------- codebook column norms from cbT [n][d]
__global__ __launch_bounds__(64) void cnorm_k(const float* __restrict__ cbT, float* __restrict__ cn)
{
  const int n = blockIdx.x; const int lane = threadIdx.x;
  float s = 0.f;
#pragma unroll
  for (int i = 0; i < 8; i++) {
    const float v = cbT[(size_t)n * 512 + lane + i * 64];
    s += v * v;
  }
#pragma unroll
  for (int off = 1; off < 64; off <<= 1) s += __shfl_xor(s, off);
  if (lane == 0) cn[n] = s;
}

// ---------------- VQ argmin
__global__ __launch_bounds__(256) void argmin_k(const float* __restrict__ scores,
    const float* __restrict__ cn, int* __restrict__ ids,
    float* __restrict__ out_ids)
{
  const int row = blockIdx.x * 4 + (threadIdx.x >> 6);
  const int lane = threadIdx.x & 63;
  const float* sr = scores + (size_t)row * 512;
  float best = 3.0e38f; int bi = 0x7fffffff;
#pragma unroll
  for (int i = 0; i < 8; i++) {
    const int n = lane + i * 64;
    const float v = cn[n] - 2.f * sr[n];
    if (v < best || (v == best && n < bi)) { best = v; bi = n; }
  }
#pragma unroll
  for (int off = 1; off < 64; off <<= 1) {
    const float ov = __shfl_xor(best, off);
    const int oi = __shfl_xor(bi, off);
    if (ov < best || (ov == best && oi < bi)) { best = ov; bi = oi; }
  }
  if (lane == 0) { ids[row] = bi; out_ids[row] = (float)bi; }
}

// ---------------- z = z_e + (q - z_e) -> out_z (+bf16); q from cbT
__global__ __launch_bounds__(128) void zq_k(const float* __restrict__ z_e,
    const float* __restrict__ cbT, const int* __restrict__ ids,
    float* __restrict__ zout, short* __restrict__ zb, float* __restrict__ dpart)
{
  __shared__ float red[2];
  const int p = blockIdx.x, t = threadIdx.x;
  const int id = ids[p];
  const float4 ze = *(const float4*)&z_e[(size_t)p * 512 + t * 4];
  const float4 q4 = *(const float4*)&cbT[(size_t)id * 512 + t * 4];
  const float4 dv = make_float4(q4.x - ze.x, q4.y - ze.y, q4.z - ze.z, q4.w - ze.w);
  const float4 z  = make_float4(ze.x + dv.x, ze.y + dv.y, ze.z + dv.z, ze.w + dv.w);
  *(float4*)&zout[(size_t)p * 512 + t * 4] = z;
  short* zo = zb + (size_t)p * 512 + t * 4;
  zo[0] = f2bf(z.x); zo[1] = f2bf(z.y); zo[2] = f2bf(z.z); zo[3] = f2bf(z.w);
  float loc = dv.x * dv.x + dv.y * dv.y + dv.z * dv.z + dv.w * dv.w;
#pragma unroll
  for (int off = 1; off < 64; off <<= 1) loc += __shfl_xor(loc, off);
  const int lane = t & 63, w = t >> 6;
  if (lane == 0) red[w] = loc;
  __syncthreads();
  if (t == 0) dpart[p] = red[0] + red[1];
}

__global__ __launch_bounds__(256) void diffred_k(const float* __restrict__ dpart,
    float* __restrict__ out_diff)
{
  __shared__ float red[4];
  const int t = threadIdx.x;
  float s = 0.f;
#pragma unroll
  for (int i = 0; i < 8; i++) s += dpart[t + i * 256];
#pragma unroll
  for (int off = 1; off < 64; off <<= 1) s += __shfl_xor(s, off);
  if ((t & 63) == 0) red[t >> 6] = s;
  __syncthreads();
  if (t == 0) out_diff[0] = (red[0] + red[1] + red[2] + red[3]) * (1.f / 1048576.f);
}

// =====================================================================
extern "C" void kernel_launch(void* const* d_in, const int* in_sizes, int n_in,
                              void* d_out, int out_size, void* d_ws, size_t ws_size,
                              hipStream_t stream)
{
  const int*   x         = (const int*)d_in[0];
  const float* embed     = (const float*)d_in[1];
  const float* enc_res_w = (const float*)d_in[2];
  const float* enc_res_b = (const float*)d_in[3];
  const float* enc_in_w  = (const float*)d_in[4];
  const float* enc_in_b  = (const float*)d_in[5];
  const float* enc_out_w = (const float*)d_in[6];
  const float* enc_out_b = (const float*)d_in[7];
  const float* enc_ln_g  = (const float*)d_in[8];
  const float* enc_ln_b  = (const float*)d_in[9];
  const float* enc_down_w= (const float*)d_in[10];
  const float* enc_down_b= (const float*)d_in[11];
  const float* e2q_w     = (const float*)d_in[12];
  const float* e2q_b     = (const float*)d_in[13];
  const float* codebook  = (const float*)d_in[14];
  const float* q2d_w     = (const float*)d_in[15];
  const float* q2d_b     = (const float*)d_in[16];
  const float* dec_res_w = (const float*)d_in[17];
  const float* dec_res_b = (const float*)d_in[18];
  const float* dec_in_w  = (const float*)d_in[19];
  const float* dec_in_b  = (const float*)d_in[20];
  const float* dec_out_w = (const float*)d_in[21];
  const float* dec_out_b = (const float*)d_in[22];
  const float* dec_ln_g  = (const float*)d_in[23];
  const float* dec_ln_b  = (const float*)d_in[24];
  const float* dec_up_w  = (const float*)d_in[25];
  const float* dec_up_b  = (const float*)d_in[26];

  float* ws = (float*)d_ws;
  float* S0   = ws;
  float* S1   = ws + SLOT;
  float* S2   = ws + 2 * SLOT;
  float* QKVb = ws + 3 * SLOT;               // scratch region (bf16 QKV + repacks)
  float* cnorm = QKVb + (size_t)8192 * 1536; // [512]
  int*   idsI  = (int*)(cnorm + 512);        // [2048]
  float* dpart = (float*)(idsI + 2048);      // [2048]

  float* out      = (float*)d_out;
  float* out_logp = out;                     // 4194304
  float* out_z    = out + 4194304;           // 1048576
  float* out_diff = out + 5242880;           // 1
  float* out_ids  = out + 5242881;           // 2048

  short* q2dWb   = (short*)out_logp;         // 786432
  short* resWb   = q2dWb + 786432;           // 1572864
  short* inWb    = resWb + 1572864;          // 1572864
  short* outWb   = inWb + 1572864;           // 524288
  short* upWb    = outWb + 524288;           // 1048576
  short* AbA     = upWb + 1048576;           // 2097152
  short* encResWb= AbA + 2097152;            // 786432 (fills logp region)
  short* AbB   = (short*)(QKVb + 8388608);   // decoder ping-pong
  // out_z region (dead until zq_k): enc in/out bf16 W + ds1 fp32 W
  short* encInWb  = (short*)out_z;           // 786432 shorts
  short* encOutWb = encInWb + 786432;        // 262144 shorts
  float* dsW      = out_z + 524288;          // 524288 floats
  // QKV stored bf16 in QKVb front
  short* QKVsh = (short*)QKVb;
  // QKVb-front repacks (dead window after enc attention)
  float* e2qT  = QKVb;                       // 786432
  float* ds2W  = QKVb + 786432;              // 524288
  float* cbT   = QKVb + 1310720;             // 262144
  // encoder bf16 activation ping-pong in QKVb front (dead before QKV output)
  short* E0    = (short*)QKVb;               // 8192*512 shorts
  short* E1    = E0 + 4194304;
  short* S2sh  = (short*)S2;                 // bf16 h / attn out

  // ---- weight conversions + repacks ----
  q2dw_k<<<3072, 256, 0, stream>>>(q2d_w, q2dWb);
  cast_k<<<768, 256, 0, stream>>>(dec_res_w, resWb, 0);
  cast_k<<<768, 256, 0, stream>>>(dec_in_w,  inWb, 0);
  cast_k<<<256, 256, 0, stream>>>(dec_out_w, outWb, 0);
  upw_k<<<4096, 256, 0, stream>>>(dec_up_w, upWb);
  cast_k<<<384, 256, 0, stream>>>(enc_res_w, encResWb, 0);
  cast_k<<<384, 256, 0, stream>>>(enc_in_w,  encInWb, 0);
  cast_k<<<128, 256, 0, stream>>>(enc_out_w, encOutWb, 0);
  downw_k<<<2048, 256, 0, stream>>>(enc_down_w, dsW);

  // ---- encoder: bf16 MFMA resblock/QKV/attn/out-proj (pre-LN, proven) ----
  embed_k<<<4096, 256, 0, stream>>>(x, embed, S0, E0);
  { dim3 g(128, 8);
    bgemm_k<<<g, 256, 0, stream>>>(E0, encResWb,          enc_res_b,        nullptr, nullptr, 8192, 512, 0, 0, 0, 1, 0, E1, 1, 0);
    bgemm_k<<<g, 256, 0, stream>>>(E1, encResWb + 262144, enc_res_b + 512,  nullptr, nullptr, 8192, 512, 0, 0, 0, 1, 0, E0, 1, 0);
    bgemm_k<<<g, 256, 0, stream>>>(E0, encResWb + 524288, enc_res_b + 1024, S0,      S1, 8192, 512, 0, 0, 0, 1, 0, S2sh, 0, 0);
  }
  { dim3 g(128, 24); // QKV reads S2sh (bf16 h), writes bf16 QKVsh
    bgemm_k<<<g, 256, 0, stream>>>(S2sh, encInWb, enc_in_b, nullptr, nullptr, 8192, 1536, 0, 0, 0, 1, 0, QKVsh, 0, 0);
  }
  battn_k<<<dim3(8, 64), 512, 0, stream>>>(QKVsh, nullptr, S2sh, 1024);
  { dim3 g(128, 8); // out-proj: bf16 attn out + res S1 -> S0 fp32
    bgemm_k<<<g, 256, 0, stream>>>(S2sh, encOutWb, enc_out_b, S1, S0, 8192, 512, 0, 0, 0, 1, 0, nullptr, 0, 0);
  }
  // QKVb dead: stage fp32 repacks
  e2qw_k<<<3072, 256, 0, stream>>>(e2q_w, e2qT);
  downw_k<<<2048, 256, 0, stream>>>(enc_down_w + 524288, ds2W);
  cbt_k<<<1024, 256, 0, stream>>>(codebook, cbT);
  cnorm_k<<<512, 64, 0, stream>>>(cbT, cnorm);
  // ---- post-LN z_e path: strictly fp32 (precision firewall) ----
  ln_k<<<2048, 256, 0, stream>>>(S0, enc_ln_g, enc_ln_b, S1, nullptr);
  launch_gemm(stream, S1, dsW, enc_down_b, nullptr, S2, 4096, 1024, 512, 0, 0, 0, 0, 1, 0, 1024, 1);
  launch_gemm(stream, S2, ds2W, enc_down_b + 512, nullptr, S0, 2048, 1024, 512, 0, 0, 0, 0, 1, 0, 1024, 1);
  launch_gemm(stream, S0, e2qT, e2q_b, nullptr, S2, 2048, 512, 512, 0, 0, 256, 0, 1, 0, 512, 3);
  // ---- VQ (fp32) ----
  launch_gemm(stream, S2, cbT, nullptr, nullptr, S1, 2048, 512, 512, 0, 0, 0, 0, 1, 0, 512, 1);
  argmin_k<<<512, 256, 0, stream>>>(S1, cnorm, idsI, out_ids);
  zq_k<<<2048, 128, 0, stream>>>(S2, cbT, idsI, out_z, AbA, dpart);
  diffred_k<<<1, 256, 0, stream>>>(dpart, out_diff);

  // ---- decoder (bf16 MFMA) ----
  { dim3 g(32, 8);
    bgemm_k<<<g, 256, 0, stream>>>(AbA, q2dWb, q2d_b, nullptr, S1, 2048, 512, 0, 256, 0, 1, 0, AbB, 1, 1);
  }
  // dec block 0 (P=2048, S=256)
  { dim3 g(32, 8); dim3 gq(32, 24);
    bgemm_k<<<g, 256, 0, stream>>>(AbB, resWb,            dec_res_b,        nullptr, S2, 2048, 512, 0, 0, 0, 1, 0, AbA, 1, 0);
    bgemm_k<<<g, 256, 0, stream>>>(AbA, resWb + 262144,   dec_res_b + 512,  nullptr, S0, 2048, 512, 0, 0, 0, 1, 0, AbB, 1, 0);
    bgemm_k<<<g, 256, 0, stream>>>(AbB, resWb + 524288,   dec_res_b + 1024, S1,      S2, 2048, 512, 0, 0, 0, 1, 0, AbA, 0, 0);
    bgemm_k<<<gq, 256, 0, stream>>>(AbA, inWb,            dec_in_b,         nullptr, nullptr, 2048, 1536, 0, 0, 0, 1, 0, QKVsh, 0, 0);
    battn_k<<<dim3(2, 64), 512, 0, stream>>>(QKVsh, nullptr, AbB, 256);
    bgemm_k<<<g, 256, 0, stream>>>(AbB, outWb,            dec_out_b,        S2, S1, 2048, 512, 0, 0, 0, 1, 0, nullptr, 0, 0);
    ln_k<<<512, 256, 0, stream>>>(S1, dec_ln_g, dec_ln_b, S2, AbA);
    bgemm_k<<<g, 256, 0, stream>>>(AbA, upWb,             dec_up_b, nullptr, S0, 2048, 512, 0, 0, 0, 2, 0, AbB, 1, 0);
    bgemm_k<<<g, 256, 0, stream>>>(AbA, upWb + 262144,    dec_up_b, nullptr, S0, 2048, 512, 0, 0, 0, 2, 1, AbB, 1, 0);
  }
  // dec block 1 (P=4096, S=512)
  { dim3 g(64, 8); dim3 gq(64, 24);
    bgemm_k<<<g, 256, 0, stream>>>(AbB, resWb + 786432,   dec_res_b + 1536, nullptr, S1, 4096, 512, 0, 0, 0, 1, 0, AbA, 1, 0);
    bgemm_k<<<g, 256, 0, stream>>>(AbA, resWb + 1048576,  dec_res_b + 2048, nullptr, S2, 4096, 512, 0, 0, 0, 1, 0, AbB, 1, 0);
    bgemm_k<<<g, 256, 0, stream>>>(AbB, resWb + 1310720,  dec_res_b + 2560, S0,      S1, 4096, 512, 0, 0, 0, 1, 0, AbA, 0, 0);
    bgemm_k<<<gq, 256, 0, stream>>>(AbA, inWb + 786432,   dec_in_b + 1536,  nullptr, nullptr, 4096, 1536, 0, 0, 0, 1, 0, QKVsh, 0, 0);
    battn_k<<<dim3(4, 64), 512, 0, stream>>>(QKVsh, nullptr, AbB, 512);
    bgemm_k<<<g, 256, 0, stream>>>(AbB, outWb + 262144,   dec_out_b + 512,  S1, S0, 4096, 512, 0, 0, 0, 1, 0, nullptr, 0, 0);
    ln_k<<<1024, 256, 0, stream>>>(S0, dec_ln_g + 512, dec_ln_b + 512, S1, AbA);
    bgemm_k<<<g, 256, 0, stream>>>(AbA, upWb + 524288,    dec_up_b + 512, nullptr, S0, 4096, 512, 0, 0, 0, 2, 0, nullptr, 0, 0);
    bgemm_k<<<g, 256, 0, stream>>>(AbA, upWb + 786432,    dec_up_b + 512, nullptr, S0, 4096, 512, 0, 0, 0, 2, 1, nullptr, 0, 0);
  }
  // ---- log_softmax -> f32 out (overwrites bf16 scratch region) ----
  lsm_k<<<2048, 256, 0, stream>>>(S0, out_logp);
}

// Round 23
// 729.376 us; speedup vs baseline: 1.0957x; 1.0957x over previous
//
#include <hip/hip_runtime.h>
#include <hip/hip_bf16.h>

// B=8 S=1024 C=512 V=512 D=512 NC=512 NF=2 H=8 TAU=1
// d_out FLOAT32: [logp 4194304][z 1048576][diff 1][ids 2048]
// Pre-LN encoder + decoder: bf16 MFMA. Post-LN z_e path (LN/ds/e2q/VQ): fp32.
// r23: revert gemm_k to 64x64 (r22's 64x32 regressed); double-buffered LDS +
// single barrier per k-step in gemm_k and bgemm_k (load-early/write-late).
// Numerics bit-identical to r21.

static constexpr size_t SLOT = 4194304; // 8192*512 floats

typedef short bf16x8 __attribute__((ext_vector_type(8)));
typedef float f32x4  __attribute__((ext_vector_type(4)));

__device__ __forceinline__ float eluf(float x) { return x > 0.f ? x : expm1f(x); }
__device__ __forceinline__ short f2bf(float v) {
  unsigned u = __float_as_uint(v);
  return (short)((u + 0x7FFFu + ((u >> 16) & 1u)) >> 16);
}
__device__ __forceinline__ float bf2f(short s) {
  return __uint_as_float(((unsigned)(unsigned short)s) << 16);
}

// ---------------- fp32 GEMM 64x64, double-buffered LDS, 1 barrier/iter.
// nseg=3 fuses k3 conv with exact rounding: r1=(s0)+bias; r2=s1+r1; r3=s2+r2.
__global__ __launch_bounds__(256) void gemm_k(
    const float* __restrict__ A, const float* __restrict__ W,
    const float* __restrict__ bias, const float* __restrict__ res,
    float* __restrict__ Y, int P, int K, int O,
    int act, int accum, int smod, int shift, int ystride, int yoff,
    int WS, int nseg)
{
  __shared__ alignas(16) float As[2][16][68];
  __shared__ alignas(16) float Bs[2][16][68];
  const int tid = threadIdx.x;
  const int bp = blockIdx.x * 64, bo = blockIdx.y * 64;
  const int tx = tid & 15, ty = tid >> 4;
  const int srow = tid >> 2, skq = (tid & 3) << 2;
  float vout[4][4], acc[4][4];
#pragma unroll
  for (int i = 0; i < 4; i++)
#pragma unroll
    for (int j = 0; j < 4; j++) acc[i][j] = 0.f;

  const float* arow = nullptr; const float* brow = nullptr; bool aok = true;
  auto seg_setup = [&](int s) {
    const int sh = (nseg == 3) ? (s - 1) : shift;
    const float* Wseg = (nseg == 3) ? (W + (size_t)s * 262144) : W;
    aok = true;
    if (smod) { const int ss = (bp + srow) & (smod - 1); aok = ((unsigned)(ss + sh) < (unsigned)smod); }
    arow = A + (size_t)(bp + srow + sh) * K;
    brow = Wseg + (size_t)(bo + srow) * WS;
  };
  seg_setup(0);
  float4 pa = aok ? *(const float4*)&arow[skq] : make_float4(0.f, 0.f, 0.f, 0.f);
  float4 pb = *(const float4*)&brow[skq];

  const int ips = K >> 4;            // iters per segment
  const int niter = nseg * ips;
  int lkk = 0, lseg = 0, cur = 0, ckk = 0, cseg = 0;

  for (int it = 0; it < niter; ++it) {
    if (act) { pa.x = eluf(pa.x); pa.y = eluf(pa.y); pa.z = eluf(pa.z); pa.w = eluf(pa.w); }
    As[cur][skq + 0][srow] = pa.x; As[cur][skq + 1][srow] = pa.y;
    As[cur][skq + 2][srow] = pa.z; As[cur][skq + 3][srow] = pa.w;
    Bs[cur][skq + 0][srow] = pb.x; Bs[cur][skq + 1][srow] = pb.y;
    Bs[cur][skq + 2][srow] = pb.z; Bs[cur][skq + 3][srow] = pb.w;
    __syncthreads();
    if (it + 1 < niter) {             // prefetch next tile (other buffer)
      lkk += 16;
      if (lkk == K) { lkk = 0; seg_setup(++lseg); }
      pa = aok ? *(const float4*)&arow[lkk + skq] : make_float4(0.f, 0.f, 0.f, 0.f);
      pb = *(const float4*)&brow[lkk + skq];
    }
#pragma unroll
    for (int kk2 = 0; kk2 < 16; kk2++) {
      const float4 av = *(const float4*)&As[cur][kk2][ty * 4];
      const float4 bv = *(const float4*)&Bs[cur][kk2][tx * 4];
      const float a_[4] = {av.x, av.y, av.z, av.w};
      const float b_[4] = {bv.x, bv.y, bv.z, bv.w};
#pragma unroll
      for (int i = 0; i < 4; i++)
#pragma unroll
        for (int j = 0; j < 4; j++) acc[i][j] += a_[i] * b_[j];
    }
    cur ^= 1;
    ckk += 16;
    if (ckk == K) {                   // segment fold (same order as r21)
      ckk = 0;
      if (cseg == 0) {
#pragma unroll
        for (int i = 0; i < 4; i++)
#pragma unroll
          for (int j = 0; j < 4; j++) {
            float t = acc[i][j];
            if (nseg == 3 && bias) t += bias[bo + tx * 4 + j];
            vout[i][j] = t;
          }
      } else {
#pragma unroll
        for (int i = 0; i < 4; i++)
#pragma unroll
          for (int j = 0; j < 4; j++) vout[i][j] = acc[i][j] + vout[i][j];
      }
#pragma unroll
      for (int i = 0; i < 4; i++)
#pragma unroll
        for (int j = 0; j < 4; j++) acc[i][j] = 0.f;
      cseg++;
    }
  }
#pragma unroll
  for (int i = 0; i < 4; i++) {
    const int p = bp + ty * 4 + i;
    const size_t yrow = (size_t)p * ystride + yoff;
#pragma unroll
    for (int j = 0; j < 4; j++) {
      const int o = bo + tx * 4 + j;
      float v = vout[i][j];
      if (nseg == 1) {
        if (bias) v += bias[o];
        if (res)  v += res[(size_t)p * O + o];
        if (accum) v += Y[yrow * O + o];
      }
      Y[yrow * O + o] = v;
    }
  }
}

static inline void launch_gemm(hipStream_t st, const float* A, const float* W,
                               const float* bias, const float* res, float* Y,
                               int P, int K, int O, int act, int accum,
                               int smod, int shift, int ystride, int yoff,
                               int WS, int nseg)
{
  dim3 g(P / 64, O / 64);
  gemm_k<<<g, 256, 0, st>>>(A, W, bias, res, Y, P, K, O, act, accum, smod, shift,
                            ystride, yoff, WS, nseg);
}

// ---------------- bf16 MFMA GEMM (K=512; k3 fused conv; Y/Yb nullable)
// dbuf LDS + load-early/write-late staging, 1 barrier per k-step.
__global__ __launch_bounds__(256) void bgemm_k(
    const short* __restrict__ A, const short* __restrict__ W,
    const float* __restrict__ bias, const float* __restrict__ res,
    float* __restrict__ Y, int P, int O, int accum,
    int smod, int shift, int ystride, int yoff,
    short* __restrict__ Yb, int bact, int k3)
{
  __shared__ short As[2][4096];
  __shared__ short Bs[2][4096];
  const int tid = threadIdx.x;
  const int lane = tid & 63, wid = tid >> 6;
  const int wr = wid >> 1, wc = wid & 1;
  const int bp = blockIdx.x * 64, bo = blockIdx.y * 64;
  f32x4 acc[2][2];
#pragma unroll
  for (int mi = 0; mi < 2; mi++)
#pragma unroll
    for (int ni = 0; ni < 2; ni++) acc[mi][ni] = (f32x4){0.f, 0.f, 0.f, 0.f};

  const int nseg = k3 ? 3 : 1;
  const int niter = nseg * 8;
  bf16x8 rA[2], rB[2];

  auto stage_load = [&](int it) {
    const int seg = it >> 3, k0 = (it & 7) << 6;
    const int sh = k3 ? (seg - 1) : shift;
    const int sm = k3 ? 256 : smod;
    const short* Wseg = W + (size_t)seg * 262144;
#pragma unroll
    for (int c0 = 0; c0 < 2; c0++) {
      const int c = tid + c0 * 256;
      const int row = c >> 3, kc = c & 7;
      const int p = bp + row;
      bf16x8 av = {0, 0, 0, 0, 0, 0, 0, 0};
      bool ok = true;
      if (sm) { const int s = p & (sm - 1); ok = ((unsigned)(s + sh) < (unsigned)sm); }
      if (ok) av = *(const bf16x8*)&A[(size_t)(p + sh) * 512 + k0 + (kc << 3)];
      rA[c0] = av;
      rB[c0] = *(const bf16x8*)&Wseg[(size_t)(bo + row) * 512 + k0 + (kc << 3)];
    }
  };
  auto stage_write = [&](int cb) {
#pragma unroll
    for (int c0 = 0; c0 < 2; c0++) {
      const int c = tid + c0 * 256;
      const int row = c >> 3, kc = c & 7;
      int soff = (row << 6) + (kc << 3); soff ^= (row & 7) << 3;
      *(bf16x8*)&As[cb][soff] = rA[c0];
      *(bf16x8*)&Bs[cb][soff] = rB[c0];
    }
  };

  stage_load(0);
  int cur = 0;
  for (int it = 0; it < niter; ++it) {
    stage_write(cur);
    __syncthreads();
    if (it + 1 < niter) stage_load(it + 1);  // loads fly during MFMA
#pragma unroll
    for (int ks = 0; ks < 2; ks++) {
      bf16x8 af[2], bfr[2];
#pragma unroll
      for (int mi = 0; mi < 2; mi++) {
        const int row = wr * 32 + mi * 16 + (lane & 15);
        int soff = (row << 6) + (ks << 5) + ((lane >> 4) << 3);
        soff ^= (row & 7) << 3;
        af[mi] = *(const bf16x8*)&As[cur][soff];
      }
#pragma unroll
      for (int ni = 0; ni < 2; ni++) {
        const int row = wc * 32 + ni * 16 + (lane & 15);
        int soff = (row << 6) + (ks << 5) + ((lane >> 4) << 3);
        soff ^= (row & 7) << 3;
        bfr[ni] = *(const bf16x8*)&Bs[cur][soff];
      }
#pragma unroll
      for (int mi = 0; mi < 2; mi++)
#pragma unroll
        for (int ni = 0; ni < 2; ni++)
          acc[mi][ni] = __builtin_amdgcn_mfma_f32_16x16x32_bf16(af[mi], bfr[ni], acc[mi][ni], 0, 0, 0);
    }
    cur ^= 1;
  }
#pragma unroll
  for (int mi = 0; mi < 2; mi++)
#pragma unroll
    for (int ni = 0; ni < 2; ni++)
#pragma unroll
      for (int r = 0; r < 4; r++) {
        const int p = bp + wr * 32 + mi * 16 + ((lane >> 4) << 2) + r;
        const int o = bo + wc * 32 + ni * 16 + (lane & 15);
        float v = acc[mi][ni][r];
        if (bias) v += bias[o];
        if (res)  v += res[(size_t)p * O + o];
        const size_t yi = ((size_t)p * ystride + yoff) * O + o;
        if (accum) v += Y[yi];
        if (Y) Y[yi] = v;
        if (Yb) Yb[yi] = f2bf(bact ? eluf(v) : v);
      }
}

// ---------------- bf16 MFMA flash attention, QBLK=128, 512 threads ----
__global__ __launch_bounds__(512) void battn_k(
    const short* __restrict__ qkv, float* __restrict__ Oa,
    short* __restrict__ Ob, int S)
{
  __shared__ short sq[8192];
  __shared__ short sk[4096];
  __shared__ short svt[4096];
  const int tid = threadIdx.x;
  const int lane = tid & 63, w = tid >> 6;
  const int bl = blockIdx.y >> 3, h = blockIdx.y & 7;
  const int q0 = blockIdx.x * 128;
  const short* base = qkv + (size_t)bl * S * 1536 + h * 64;

  {
    const int row = tid >> 2, c0 = (tid & 3) << 4;
    const short* src = base + (size_t)(q0 + row) * 1536 + c0;
    bf16x8 v0 = *(const bf16x8*)&src[0];
    bf16x8 v1 = *(const bf16x8*)&src[8];
#pragma unroll
    for (int e = 0; e < 8; e++) {
      v0[e] = f2bf(bf2f(v0[e]) * 0.125f);
      v1[e] = f2bf(bf2f(v1[e]) * 0.125f);
    }
    int s0 = (row << 6) + c0;       s0 ^= (row & 7) << 3;
    int s1 = (row << 6) + c0 + 8;   s1 ^= (row & 7) << 3;
    *(bf16x8*)&sq[s0] = v0; *(bf16x8*)&sq[s1] = v1;
  }
  __syncthreads();
  bf16x8 af[2];
#pragma unroll
  for (int ks = 0; ks < 2; ks++) {
    const int row = (w << 4) + (lane & 15);
    int soff = (row << 6) + (((lane >> 4) + 4 * ks) << 3);
    soff ^= (row & 7) << 3;
    af[ks] = *(const bf16x8*)&sq[soff];
  }

  f32x4 oacc[4];
#pragma unroll
  for (int dt = 0; dt < 4; dt++) oacc[dt] = (f32x4){0.f, 0.f, 0.f, 0.f};
  float m[4], l[4];
#pragma unroll
  for (int r = 0; r < 4; r++) { m[r] = -INFINITY; l[r] = 0.f; }

  for (int t0 = 0; t0 < S; t0 += 64) {
    __syncthreads();
    if (tid < 256) {
      const int row = tid >> 2, c0 = (tid & 3) << 4;
      const short* ksrc = base + (size_t)(t0 + row) * 1536 + 512 + c0;
      int s0 = (row << 6) + c0;       s0 ^= (row & 7) << 3;
      int s1 = (row << 6) + c0 + 8;   s1 ^= (row & 7) << 3;
      *(bf16x8*)&sk[s0] = *(const bf16x8*)&ksrc[0];
      *(bf16x8*)&sk[s1] = *(const bf16x8*)&ksrc[8];
    } else {
      const int t = tid - 256;
      const int row = t >> 2, c0 = (t & 3) << 4;
      const short* vsrc = base + (size_t)(t0 + row) * 1536 + 1024 + c0;
      const bf16x8 va0 = *(const bf16x8*)&vsrc[0];
      const bf16x8 va1 = *(const bf16x8*)&vsrc[8];
#pragma unroll
      for (int i = 0; i < 16; i++) {
        const int dd = c0 + i;
        int so = (dd << 6) + row;
        so ^= ((dd & 7) ^ (((dd >> 4) & 3) << 1)) << 3;
        svt[so] = (i < 8) ? va0[i & 7] : va1[i & 7];
      }
    }
    __syncthreads();
    f32x4 sacc[4];
#pragma unroll
    for (int ct = 0; ct < 4; ct++) {
      sacc[ct] = (f32x4){0.f, 0.f, 0.f, 0.f};
#pragma unroll
      for (int ks = 0; ks < 2; ks++) {
        const int row = (ct << 4) + (lane & 15);
        int soff = (row << 6) + (((lane >> 4) + 4 * ks) << 3);
        soff ^= (row & 7) << 3;
        const bf16x8 bk = *(const bf16x8*)&sk[soff];
        sacc[ct] = __builtin_amdgcn_mfma_f32_16x16x32_bf16(af[ks], bk, sacc[ct], 0, 0, 0);
      }
    }
    float p[4][4]; float corr[4];
#pragma unroll
    for (int r = 0; r < 4; r++) {
      float mx = fmaxf(fmaxf(sacc[0][r], sacc[1][r]), fmaxf(sacc[2][r], sacc[3][r]));
      mx = fmaxf(mx, __shfl_xor(mx, 1));
      mx = fmaxf(mx, __shfl_xor(mx, 2));
      mx = fmaxf(mx, __shfl_xor(mx, 4));
      mx = fmaxf(mx, __shfl_xor(mx, 8));
      const float newm = fmaxf(m[r], mx);
      corr[r] = expf(m[r] - newm);
      float psum = 0.f;
#pragma unroll
      for (int ct = 0; ct < 4; ct++) { p[ct][r] = expf(sacc[ct][r] - newm); psum += p[ct][r]; }
      psum += __shfl_xor(psum, 1);
      psum += __shfl_xor(psum, 2);
      psum += __shfl_xor(psum, 4);
      psum += __shfl_xor(psum, 8);
      l[r] = l[r] * corr[r] + psum;
      m[r] = newm;
#pragma unroll
      for (int dt = 0; dt < 4; dt++) oacc[dt][r] *= corr[r];
    }
#pragma unroll
    for (int r = 0; r < 4; r++)
#pragma unroll
      for (int ct = 0; ct < 4; ct++) {
        const int q = (w << 4) + ((lane >> 4) << 2) + r;
        const int kv = (ct << 4) + (lane & 15);
        int so = (q << 6) + kv; so ^= (q & 7) << 3;
        sq[so] = f2bf(p[ct][r]);
      }
#pragma unroll
    for (int ks = 0; ks < 2; ks++) {
      const int prow = (w << 4) + (lane & 15);
      int poff = (prow << 6) + (((lane >> 4) + 4 * ks) << 3);
      poff ^= (prow & 7) << 3;
      const bf16x8 pa = *(const bf16x8*)&sq[poff];
#pragma unroll
      for (int dt = 0; dt < 4; dt++) {
        const int vrow = (dt << 4) + (lane & 15);
        int voff = (vrow << 6) + (((lane >> 4) + 4 * ks) << 3);
        voff ^= ((vrow & 7) ^ (((vrow >> 4) & 3) << 1)) << 3;
        const bf16x8 bv = *(const bf16x8*)&svt[voff];
        oacc[dt] = __builtin_amdgcn_mfma_f32_16x16x32_bf16(pa, bv, oacc[dt], 0, 0, 0);
      }
    }
  }
#pragma unroll
  for (int r = 0; r < 4; r++) {
    const float inv = 1.f / l[r];
    const int q = (w << 4) + ((lane >> 4) << 2) + r;
    const size_t rowbase = (size_t)(bl * S + q0 + q) * 512 + h * 64;
#pragma unroll
    for (int dt = 0; dt < 4; dt++) {
      const int d = (dt << 4) + (lane & 15);
      const float ov = oacc[dt][r] * inv;
      if (Oa) Oa[rowbase + d] = ov;
      if (Ob) Ob[rowbase + d] = f2bf(ov);
    }
  }
}

// ---------------- fp32 -> bf16 cast (weights)
__global__ __launch_bounds__(256) void cast_k(const float* __restrict__ src,
    short* __restrict__ dst, int act)
{
  const size_t i = ((size_t)blockIdx.x * 256 + threadIdx.x) * 8;
  float4 a = *(const float4*)&src[i];
  float4 b = *(const float4*)&src[i + 4];
  if (act) {
    a.x = eluf(a.x); a.y = eluf(a.y); a.z = eluf(a.z); a.w = eluf(a.w);
    b.x = eluf(b.x); b.y = eluf(b.y); b.z = eluf(b.z); b.w = eluf(b.w);
  }
  bf16x8 o;
  o[0] = f2bf(a.x); o[1] = f2bf(a.y); o[2] = f2bf(a.z); o[3] = f2bf(a.w);
  o[4] = f2bf(b.x); o[5] = f2bf(b.y); o[6] = f2bf(b.z); o[7] = f2bf(b.w);
  *(bf16x8*)&dst[i] = o;
}

// q2d_w [512 o][512 k][3] -> 3 mats [512][512] bf16
__global__ __launch_bounds__(256) void q2dw_k(const float* __restrict__ src, short* __restrict__ dst)
{
  const int idx = blockIdx.x * 256 + threadIdx.x;
  const int w = idx >> 18, rem = idx & 262143;
  const int o = rem >> 9, k = rem & 511;
  dst[idx] = f2bf(src[(size_t)o * 1536 + k * 3 + w]);
}

// dec_up_w [NF][512 i][512 o][2 k] -> 4 mats [(f*2+k)][512 o][512 i] bf16
__global__ __launch_bounds__(256) void upw_k(const float* __restrict__ src, short* __restrict__ dst)
{
  const int idx = blockIdx.x * 256 + threadIdx.x;
  const int mi = idx >> 18, f = mi >> 1, kq = mi & 1;
  const int rem = idx & 262143;
  const int o = rem >> 9, i2 = rem & 511;
  dst[idx] = f2bf(src[(size_t)f * 524288 + (size_t)i2 * 1024 + o * 2 + kq]);
}

// down weight [512 o][512 i][2 ks] -> fp32 [512 o][ks*512+i]
__global__ __launch_bounds__(256) void downw_k(const float* __restrict__ src, float* __restrict__ dst)
{
  const int idx = blockIdx.x * 256 + threadIdx.x; // 524288
  const int i = idx & 511, ks = (idx >> 9) & 1, o = idx >> 10;
  dst[idx] = src[(size_t)o * 1024 + i * 2 + ks];
}

// e2q_w [512 o][512 k][3 w] -> fp32 [3 w][512 o][512 k]
__global__ __launch_bounds__(256) void e2qw_k(const float* __restrict__ src, float* __restrict__ dst)
{
  const int idx = blockIdx.x * 256 + threadIdx.x; // 786432
  const int w = idx >> 18, rem = idx & 262143;
  const int o = rem >> 9, k = rem & 511;
  dst[idx] = src[(size_t)o * 1536 + k * 3 + w];
}

// codebook [512 d][512 n] -> fp32 cbT [512 n][512 d]
__global__ __launch_bounds__(256) void cbt_k(const float* __restrict__ src, float* __restrict__ dst)
{
  const int idx = blockIdx.x * 256 + threadIdx.x; // 262144
  const int n = idx >> 9, d = idx & 511;
  dst[idx] = src[(size_t)d * 512 + n];
}

// ---------------- layernorm over C=512, optional bf16 out
__global__ __launch_bounds__(256) void ln_k(const float* __restrict__ X,
    const float* __restrict__ g, const float* __restrict__ bta,
    float* __restrict__ Y, short* __restrict__ Ob)
{
  const int row = blockIdx.x * 4 + (threadIdx.x >> 6);
  const int lane = threadIdx.x & 63;
  const float* x = X + (size_t)row * 512;
  float v[8]; float s = 0.f;
#pragma unroll
  for (int i = 0; i < 8; i++) { v[i] = x[lane + i * 64]; s += v[i]; }
#pragma unroll
  for (int off = 1; off < 64; off <<= 1) s += __shfl_xor(s, off);
  const float mean = s * (1.f / 512.f);
  float vs = 0.f;
#pragma unroll
  for (int i = 0; i < 8; i++) { const float d = v[i] - mean; vs += d * d; }
#pragma unroll
  for (int off = 1; off < 64; off <<= 1) vs += __shfl_xor(vs, off);
  const float rstd = 1.f / sqrtf(vs * (1.f / 512.f) + 1e-5f);
  float* y = Y ? (Y + (size_t)row * 512) : nullptr;
#pragma unroll
  for (int i = 0; i < 8; i++) {
    const int c = lane + i * 64;
    const float o = (v[i] - mean) * rstd * g[c] + bta[c];
    if (y) y[c] = o;
    if (Ob) Ob[(size_t)row * 512 + c] = f2bf(o);
  }
}

// ---------------- log_softmax over C=512 -> f32 out
__global__ __launch_bounds__(256) void lsm_k(const float* __restrict__ X,
    float* __restrict__ out)
{
  const int row = blockIdx.x * 4 + (threadIdx.x >> 6);
  const int lane = threadIdx.x & 63;
  const float* x = X + (size_t)row * 512;
  float v[8]; float mx = -3.0e38f;
#pragma unroll
  for (int i = 0; i < 8; i++) { v[i] = x[lane + i * 64]; mx = fmaxf(mx, v[i]); }
#pragma unroll
  for (int off = 1; off < 64; off <<= 1) mx = fmaxf(mx, __shfl_xor(mx, off));
  float sum = 0.f;
#pragma unroll
  for (int i = 0; i < 8; i++) sum += expf(v[i] - mx);
#pragma unroll
  for (int off = 1; off < 64; off <<= 1) sum += __shfl_xor(sum, off);
  const float ls = logf(sum);
  float* y = out + (size_t)row * 512;
#pragma unroll
  for (int i = 0; i < 8; i++) y[lane + i * 64] = v[i] - mx - ls;
}

// ---------------- embedding gather (+bf16 elu copy)
__global__ __launch_bounds__(256) void embed_k(const int* __restrict__ x,
    const float* __restrict__ emb, float* __restrict__ out, short* __restrict__ outb)
{
  const int i = blockIdx.x * 256 + threadIdx.x;
  const int p = i >> 7, c4 = i & 127;
  const int id = x[p];
  const float4 v = *(const float4*)&emb[(size_t)id * 512 + c4 * 4];
  *(float4*)&out[(size_t)p * 512 + c4 * 4] = v;
  short* ob = outb + (size_t)p * 512 + c4 * 4;
  ob[0] = f2bf(eluf(v.x)); ob[1] = f2bf(eluf(v.y));
  ob[2] = f2bf(eluf(v.z)); ob[3] = f2bf(eluf(v.w));
}

// ---------------- codebook column norms from cbT [n][d]
__global__ __launch_bounds__(64) void cnorm_k(const float* __restrict__ cbT, float* __restrict__ cn)
{
  const int n = blockIdx.x; const int lane = threadIdx.x;
  float s = 0.f;
#pragma unroll
  for (int i = 0; i < 8; i++) {
    const float v = cbT[(size_t)n * 512 + lane + i * 64];
    s += v * v;
  }
#pragma unroll
  for (int off = 1; off < 64; off <<= 1) s += __shfl_xor(s, off);
  if (lane == 0) cn[n] = s;
}

// ---------------- VQ argmin
__global__ __launch_bounds__(256) void argmin_k(const float* __restrict__ scores,
    const float* __restrict__ cn, int* __restrict__ ids,
    float* __restrict__ out_ids)
{
  const int row = blockIdx.x * 4 + (threadIdx.x >> 6);
  const int lane = threadIdx.x & 63;
  const float* sr = scores + (size_t)row * 512;
  float best = 3.0e38f; int bi = 0x7fffffff;
#pragma unroll
  for (int i = 0; i < 8; i++) {
    const int n = lane + i * 64;
    const float v = cn[n] - 2.f * sr[n];
    if (v < best || (v == best && n < bi)) { best = v; bi = n; }
  }
#pragma unroll
  for (int off = 1; off < 64; off <<= 1) {
    const float ov = __shfl_xor(best, off);
    const int oi = __shfl_xor(bi, off);
    if (ov < best || (ov == best && oi < bi)) { best = ov; bi = oi; }
  }
  if (lane == 0) { ids[row] = bi; out_ids[row] = (float)bi; }
}

// ---------------- z = z_e + (q - z_e) -> out_z (+bf16); q from cbT
__global__ __launch_bounds__(128) void zq_k(const float* __restrict__ z_e,
    const float* __restrict__ cbT, const int* __restrict__ ids,
    float* __restrict__ zout, short* __restrict__ zb, float* __restrict__ dpart)
{
  __shared__ float red[2];
  const int p = blockIdx.x, t = threadIdx.x;
  const int id = ids[p];
  const float4 ze = *(const float4*)&z_e[(size_t)p * 512 + t * 4];
  const float4 q4 = *(const float4*)&cbT[(size_t)id * 512 + t * 4];
  const float4 dv = make_float4(q4.x - ze.x, q4.y - ze.y, q4.z - ze.z, q4.w - ze.w);
  const float4 z  = make_float4(ze.x + dv.x, ze.y + dv.y, ze.z + dv.z, ze.w + dv.w);
  *(float4*)&zout[(size_t)p * 512 + t * 4] = z;
  short* zo = zb + (size_t)p * 512 + t * 4;
  zo[0] = f2bf(z.x); zo[1] = f2bf(z.y); zo[2] = f2bf(z.z); zo[3] = f2bf(z.w);
  float loc = dv.x * dv.x + dv.y * dv.y + dv.z * dv.z + dv.w * dv.w;
#pragma unroll
  for (int off = 1; off < 64; off <<= 1) loc += __shfl_xor(loc, off);
  const int lane = t & 63, w = t >> 6;
  if (lane == 0) red[w] = loc;
  __syncthreads();
  if (t == 0) dpart[p] = red[0] + red[1];
}

__global__ __launch_bounds__(256) void diffred_k(const float* __restrict__ dpart,
    float* __restrict__ out_diff)
{
  __shared__ float red[4];
  const int t = threadIdx.x;
  float s = 0.f;
#pragma unroll
  for (int i = 0; i < 8; i++) s += dpart[t + i * 256];
#pragma unroll
  for (int off = 1; off < 64; off <<= 1) s += __shfl_xor(s, off);
  if ((t & 63) == 0) red[t >> 6] = s;
  __syncthreads();
  if (t == 0) out_diff[0] = (red[0] + red[1] + red[2] + red[3]) * (1.f / 1048576.f);
}

// =====================================================================
extern "C" void kernel_launch(void* const* d_in, const int* in_sizes, int n_in,
                              void* d_out, int out_size, void* d_ws, size_t ws_size,
                              hipStream_t stream)
{
  const int*   x         = (const int*)d_in[0];
  const float* embed     = (const float*)d_in[1];
  const float* enc_res_w = (const float*)d_in[2];
  const float* enc_res_b = (const float*)d_in[3];
  const float* enc_in_w  = (const float*)d_in[4];
  const float* enc_in_b  = (const float*)d_in[5];
  const float* enc_out_w = (const float*)d_in[6];
  const float* enc_out_b = (const float*)d_in[7];
  const float* enc_ln_g  = (const float*)d_in[8];
  const float* enc_ln_b  = (const float*)d_in[9];
  const float* enc_down_w= (const float*)d_in[10];
  const float* enc_down_b= (const float*)d_in[11];
  const float* e2q_w     = (const float*)d_in[12];
  const float* e2q_b     = (const float*)d_in[13];
  const float* codebook  = (const float*)d_in[14];
  const float* q2d_w     = (const float*)d_in[15];
  const float* q2d_b     = (const float*)d_in[16];
  const float* dec_res_w = (const float*)d_in[17];
  const float* dec_res_b = (const float*)d_in[18];
  const float* dec_in_w  = (const float*)d_in[19];
  const float* dec_in_b  = (const float*)d_in[20];
  const float* dec_out_w = (const float*)d_in[21];
  const float* dec_out_b = (const float*)d_in[22];
  const float* dec_ln_g  = (const float*)d_in[23];
  const float* dec_ln_b  = (const float*)d_in[24];
  const float* dec_up_w  = (const float*)d_in[25];
  const float* dec_up_b  = (const float*)d_in[26];

  float* ws = (float*)d_ws;
  float* S0   = ws;
  float* S1   = ws + SLOT;
  float* S2   = ws + 2 * SLOT;
  float* QKVb = ws + 3 * SLOT;               // scratch region (bf16 QKV + repacks)
  float* cnorm = QKVb + (size_t)8192 * 1536; // [512]
  int*   idsI  = (int*)(cnorm + 512);        // [2048]
  float* dpart = (float*)(idsI + 2048);      // [2048]

  float* out      = (float*)d_out;
  float* out_logp = out;                     // 4194304
  float* out_z    = out + 4194304;           // 1048576
  float* out_diff = out + 5242880;           // 1
  float* out_ids  = out + 5242881;           // 2048

  short* q2dWb   = (short*)out_logp;         // 786432
  short* resWb   = q2dWb + 786432;           // 1572864
  short* inWb    = resWb + 1572864;          // 1572864
  short* outWb   = inWb + 1572864;           // 524288
  short* upWb    = outWb + 524288;           // 1048576
  short* AbA     = upWb + 1048576;           // 2097152
  short* encResWb= AbA + 2097152;            // 786432 (fills logp region)
  short* AbB   = (short*)(QKVb + 8388608);   // decoder ping-pong
  // out_z region (dead until zq_k): enc in/out bf16 W + ds1 fp32 W
  short* encInWb  = (short*)out_z;           // 786432 shorts
  short* encOutWb = encInWb + 786432;        // 262144 shorts
  float* dsW      = out_z + 524288;          // 524288 floats
  // QKV stored bf16 in QKVb front
  short* QKVsh = (short*)QKVb;
  // QKVb-front repacks (dead window after enc attention)
  float* e2qT  = QKVb;                       // 786432
  float* ds2W  = QKVb + 786432;              // 524288
  float* cbT   = QKVb + 1310720;             // 262144
  // encoder bf16 activation ping-pong in QKVb front (dead before QKV output)
  short* E0    = (short*)QKVb;               // 8192*512 shorts
  short* E1    = E0 + 4194304;
  short* S2sh  = (short*)S2;                 // bf16 h / attn out

  // ---- weight conversions + repacks ----
  q2dw_k<<<3072, 256, 0, stream>>>(q2d_w, q2dWb);
  cast_k<<<768, 256, 0, stream>>>(dec_res_w, resWb, 0);
  cast_k<<<768, 256, 0, stream>>>(dec_in_w,  inWb, 0);
  cast_k<<<256, 256, 0, stream>>>(dec_out_w, outWb, 0);
  upw_k<<<4096, 256, 0, stream>>>(dec_up_w, upWb);
  cast_k<<<384, 256, 0, stream>>>(enc_res_w, encResWb, 0);
  cast_k<<<384, 256, 0, stream>>>(enc_in_w,  encInWb, 0);
  cast_k<<<128, 256, 0, stream>>>(enc_out_w, encOutWb, 0);
  downw_k<<<2048, 256, 0, stream>>>(enc_down_w, dsW);

  // ---- encoder: bf16 MFMA resblock/QKV/attn/out-proj (pre-LN, proven) ----
  embed_k<<<4096, 256, 0, stream>>>(x, embed, S0, E0);
  { dim3 g(128, 8);
    bgemm_k<<<g, 256, 0, stream>>>(E0, encResWb,          enc_res_b,        nullptr, nullptr, 8192, 512, 0, 0, 0, 1, 0, E1, 1, 0);
    bgemm_k<<<g, 256, 0, stream>>>(E1, encResWb + 262144, enc_res_b + 512,  nullptr, nullptr, 8192, 512, 0, 0, 0, 1, 0, E0, 1, 0);
    bgemm_k<<<g, 256, 0, stream>>>(E0, encResWb + 524288, enc_res_b + 1024, S0,      S1, 8192, 512, 0, 0, 0, 1, 0, S2sh, 0, 0);
  }
  { dim3 g(128, 24); // QKV reads S2sh (bf16 h), writes bf16 QKVsh
    bgemm_k<<<g, 256, 0, stream>>>(S2sh, encInWb, enc_in_b, nullptr, nullptr, 8192, 1536, 0, 0, 0, 1, 0, QKVsh, 0, 0);
  }
  battn_k<<<dim3(8, 64), 512, 0, stream>>>(QKVsh, nullptr, S2sh, 1024);
  { dim3 g(128, 8); // out-proj: bf16 attn out + res S1 -> S0 fp32
    bgemm_k<<<g, 256, 0, stream>>>(S2sh, encOutWb, enc_out_b, S1, S0, 8192, 512, 0, 0, 0, 1, 0, nullptr, 0, 0);
  }
  // QKVb dead: stage fp32 repacks
  e2qw_k<<<3072, 256, 0, stream>>>(e2q_w, e2qT);
  downw_k<<<2048, 256, 0, stream>>>(enc_down_w + 524288, ds2W);
  cbt_k<<<1024, 256, 0, stream>>>(codebook, cbT);
  cnorm_k<<<512, 64, 0, stream>>>(cbT, cnorm);
  // ---- post-LN z_e path: strictly fp32 (precision firewall) ----
  ln_k<<<2048, 256, 0, stream>>>(S0, enc_ln_g, enc_ln_b, S1, nullptr);
  launch_gemm(stream, S1, dsW, enc_down_b, nullptr, S2, 4096, 1024, 512, 0, 0, 0, 0, 1, 0, 1024, 1);
  launch_gemm(stream, S2, ds2W, enc_down_b + 512, nullptr, S0, 2048, 1024, 512, 0, 0, 0, 0, 1, 0, 1024, 1);
  launch_gemm(stream, S0, e2qT, e2q_b, nullptr, S2, 2048, 512, 512, 0, 0, 256, 0, 1, 0, 512, 3);
  // ---- VQ (fp32) ----
  launch_gemm(stream, S2, cbT, nullptr, nullptr, S1, 2048, 512, 512, 0, 0, 0, 0, 1, 0, 512, 1);
  argmin_k<<<512, 256, 0, stream>>>(S1, cnorm, idsI, out_ids);
  zq_k<<<2048, 128, 0, stream>>>(S2, cbT, idsI, out_z, AbA, dpart);
  diffred_k<<<1, 256, 0, stream>>>(dpart, out_diff);

  // ---- decoder (bf16 MFMA) ----
  { dim3 g(32, 8);
    bgemm_k<<<g, 256, 0, stream>>>(AbA, q2dWb, q2d_b, nullptr, S1, 2048, 512, 0, 256, 0, 1, 0, AbB, 1, 1);
  }
  // dec block 0 (P=2048, S=256)
  { dim3 g(32, 8); dim3 gq(32, 24);
    bgemm_k<<<g, 256, 0, stream>>>(AbB, resWb,            dec_res_b,        nullptr, S2, 2048, 512, 0, 0, 0, 1, 0, AbA, 1, 0);
    bgemm_k<<<g, 256, 0, stream>>>(AbA, resWb + 262144,   dec_res_b + 512,  nullptr, S0, 2048, 512, 0, 0, 0, 1, 0, AbB, 1, 0);
    bgemm_k<<<g, 256, 0, stream>>>(AbB, resWb + 524288,   dec_res_b + 1024, S1,      S2, 2048, 512, 0, 0, 0, 1, 0, AbA, 0, 0);
    bgemm_k<<<gq, 256, 0, stream>>>(AbA, inWb,            dec_in_b,         nullptr, nullptr, 2048, 1536, 0, 0, 0, 1, 0, QKVsh, 0, 0);
    battn_k<<<dim3(2, 64), 512, 0, stream>>>(QKVsh, nullptr, AbB, 256);
    bgemm_k<<<g, 256, 0, stream>>>(AbB, outWb,            dec_out_b,        S2, S1, 2048, 512, 0, 0, 0, 1, 0, nullptr, 0, 0);
    ln_k<<<512, 256, 0, stream>>>(S1, dec_ln_g, dec_ln_b, S2, AbA);
    bgemm_k<<<g, 256, 0, stream>>>(AbA, upWb,             dec_up_b, nullptr, S0, 2048, 512, 0, 0, 0, 2, 0, AbB, 1, 0);
    bgemm_k<<<g, 256, 0, stream>>>(AbA, upWb + 262144,    dec_up_b, nullptr, S0, 2048, 512, 0, 0, 0, 2, 1, AbB, 1, 0);
  }
  // dec block 1 (P=4096, S=512)
  { dim3 g(64, 8); dim3 gq(64, 24);
    bgemm_k<<<g, 256, 0, stream>>>(AbB, resWb + 786432,   dec_res_b + 1536, nullptr, S1, 4096, 512, 0, 0, 0, 1, 0, AbA, 1, 0);
    bgemm_k<<<g, 256, 0, stream>>>(AbA, resWb + 1048576,  dec_res_b + 2048, nullptr, S2, 4096, 512, 0, 0, 0, 1, 0, AbB, 1, 0);
    bgemm_k<<<g, 256, 0, stream>>>(AbB, resWb + 1310720,  dec_res_b + 2560, S0,      S1, 4096, 512, 0, 0, 0, 1, 0, AbA, 0, 0);
    bgemm_k<<<gq, 256, 0, stream>>>(AbA, inWb + 786432,   dec_in_b + 1536,  nullptr, nullptr, 4096, 1536, 0, 0, 0, 1, 0, QKVsh, 0, 0);
    battn_k<<<dim3(4, 64), 512, 0, stream>>>(QKVsh, nullptr, AbB, 512);
    bgemm_k<<<g, 256, 0, stream>>>(AbB, outWb + 262144,   dec_out_b + 512,  S1, S0, 4096, 512, 0, 0, 0, 1, 0, nullptr, 0, 0);
    ln_k<<<1024, 256, 0, stream>>>(S0, dec_ln_g + 512, dec_ln_b + 512, S1, AbA);
    bgemm_k<<<g, 256, 0, stream>>>(AbA, upWb + 524288,    dec_up_b + 512, nullptr, S0, 4096, 512, 0, 0, 0, 2, 0, nullptr, 0, 0);
    bgemm_k<<<g, 256, 0, stream>>>(AbA, upWb + 786432,    dec_up_b + 512, nullptr, S0, 4096, 512, 0, 0, 0, 2, 1, nullptr, 0, 0);
  }
  // ---- log_softmax -> f32 out (overwrites bf16 scratch region) ----
  lsm_k<<<2048, 256, 0, stream>>>(S0, out_logp);
}

// Round 24
// 694.872 us; speedup vs baseline: 1.1501x; 1.0497x over previous
//
#include <hip/hip_runtime.h>
#include <hip/hip_bf16.h>

// B=8 S=1024 C=512 V=512 D=512 NC=512 NF=2 H=8 TAU=1
// d_out FLOAT32: [logp 4194304][z 1048576][diff 1][ids 2048]
// Pre-LN encoder + decoder: bf16 MFMA. Post-LN z_e path (LN/ds/e2q/VQ): fp32.
// r24: e2q k3-conv split over gridDim.z=3 (per-tap partials, exact-order
// combine kernel) -> 3x occupancy; decoder up-conv tap pairs merged via
// gridDim.z=2. Numerics bit-identical to r23.

static constexpr size_t SLOT = 4194304; // 8192*512 floats

typedef short bf16x8 __attribute__((ext_vector_type(8)));
typedef float f32x4  __attribute__((ext_vector_type(4)));

__device__ __forceinline__ float eluf(float x) { return x > 0.f ? x : expm1f(x); }
__device__ __forceinline__ short f2bf(float v) {
  unsigned u = __float_as_uint(v);
  return (short)((u + 0x7FFFu + ((u >> 16) & 1u)) >> 16);
}
__device__ __forceinline__ float bf2f(short s) {
  return __uint_as_float(((unsigned)(unsigned short)s) << 16);
}

// ---------------- fp32 GEMM 64x64, double-buffered LDS, 1 barrier/iter.
// gridDim.z==3: e2q k3 seg-split — block z computes tap z's raw partial
// (bias/res/accum suppressed) into plane Y + z*P*O; combine kernel folds.
__global__ __launch_bounds__(256) void gemm_k(
    const float* __restrict__ A, const float* __restrict__ W,
    const float* __restrict__ bias, const float* __restrict__ res,
    float* __restrict__ Y, int P, int K, int O,
    int act, int accum, int smod, int shift, int ystride, int yoff,
    int WS)
{
  __shared__ alignas(16) float As[2][16][68];
  __shared__ alignas(16) float Bs[2][16][68];
  if (gridDim.z > 1) {            // per-tap split (e2q)
    shift = (int)blockIdx.z - 1;
    W += (size_t)blockIdx.z * 262144;
    Y += (size_t)blockIdx.z * ((size_t)P * O);
    bias = nullptr; res = nullptr; accum = 0;
  }
  const int tid = threadIdx.x;
  const int bp = blockIdx.x * 64, bo = blockIdx.y * 64;
  const int tx = tid & 15, ty = tid >> 4;
  const int srow = tid >> 2, skq = (tid & 3) << 2;
  float acc[4][4];
#pragma unroll
  for (int i = 0; i < 4; i++)
#pragma unroll
    for (int j = 0; j < 4; j++) acc[i][j] = 0.f;

  bool aok = true;
  if (smod) { const int s = (bp + srow) & (smod - 1); aok = ((unsigned)(s + shift) < (unsigned)smod); }
  const float* arow = A + (size_t)(bp + srow + shift) * K;
  const float* brow = W + (size_t)(bo + srow) * WS;

  float4 pa = aok ? *(const float4*)&arow[skq] : make_float4(0.f, 0.f, 0.f, 0.f);
  float4 pb = *(const float4*)&brow[skq];

  const int niter = K >> 4;
  int cur = 0;
  for (int it = 0; it < niter; ++it) {
    if (act) { pa.x = eluf(pa.x); pa.y = eluf(pa.y); pa.z = eluf(pa.z); pa.w = eluf(pa.w); }
    As[cur][skq + 0][srow] = pa.x; As[cur][skq + 1][srow] = pa.y;
    As[cur][skq + 2][srow] = pa.z; As[cur][skq + 3][srow] = pa.w;
    Bs[cur][skq + 0][srow] = pb.x; Bs[cur][skq + 1][srow] = pb.y;
    Bs[cur][skq + 2][srow] = pb.z; Bs[cur][skq + 3][srow] = pb.w;
    __syncthreads();
    if (it + 1 < niter) {
      const int kk = (it + 1) << 4;
      pa = aok ? *(const float4*)&arow[kk + skq] : make_float4(0.f, 0.f, 0.f, 0.f);
      pb = *(const float4*)&brow[kk + skq];
    }
#pragma unroll
    for (int kk2 = 0; kk2 < 16; kk2++) {
      const float4 av = *(const float4*)&As[cur][kk2][ty * 4];
      const float4 bv = *(const float4*)&Bs[cur][kk2][tx * 4];
      const float a_[4] = {av.x, av.y, av.z, av.w};
      const float b_[4] = {bv.x, bv.y, bv.z, bv.w};
#pragma unroll
      for (int i = 0; i < 4; i++)
#pragma unroll
        for (int j = 0; j < 4; j++) acc[i][j] += a_[i] * b_[j];
    }
    cur ^= 1;
  }
#pragma unroll
  for (int i = 0; i < 4; i++) {
    const int p = bp + ty * 4 + i;
    const size_t yrow = (size_t)p * ystride + yoff;
#pragma unroll
    for (int j = 0; j < 4; j++) {
      const int o = bo + tx * 4 + j;
      float v = acc[i][j];
      if (bias) v += bias[o];
      if (res)  v += res[(size_t)p * O + o];
      if (accum) v += Y[yrow * O + o];
      Y[yrow * O + o] = v;
    }
  }
}

static inline void launch_gemm(hipStream_t st, const float* A, const float* W,
                               const float* bias, const float* res, float* Y,
                               int P, int K, int O, int act, int accum,
                               int smod, int shift, int ystride, int yoff,
                               int WS)
{
  dim3 g(P / 64, O / 64);
  gemm_k<<<g, 256, 0, st>>>(A, W, bias, res, Y, P, K, O, act, accum, smod, shift,
                            ystride, yoff, WS);
}

// e2q combine: exact r23 fold order t=(p0+bias); t=p1+t; t=p2+t
__global__ __launch_bounds__(256) void e2qc_k(const float* __restrict__ pl,
    const float* __restrict__ bias, float* __restrict__ out)
{
  const int i = (blockIdx.x * 256 + threadIdx.x) * 4;
  const int o = i & 511;
  const float4 p0 = *(const float4*)&pl[i];
  const float4 p1 = *(const float4*)&pl[i + 1048576];
  const float4 p2 = *(const float4*)&pl[i + 2097152];
  const float4 bb = *(const float4*)&bias[o];
  float4 t;
  t.x = p0.x + bb.x; t.y = p0.y + bb.y; t.z = p0.z + bb.z; t.w = p0.w + bb.w;
  t.x = p1.x + t.x;  t.y = p1.y + t.y;  t.z = p1.z + t.z;  t.w = p1.w + t.w;
  t.x = p2.x + t.x;  t.y = p2.y + t.y;  t.z = p2.z + t.z;  t.w = p2.w + t.w;
  *(float4*)&out[i] = t;
}

// ---------------- bf16 MFMA GEMM (K=512; k3 fused conv; Y/Yb nullable)
// dbuf LDS + load-early/write-late staging, 1 barrier per k-step.
// gridDim.z>1: independent tap merge — W += z*262144, yoff += z.
__global__ __launch_bounds__(256) void bgemm_k(
    const short* __restrict__ A, const short* __restrict__ W,
    const float* __restrict__ bias, const float* __restrict__ res,
    float* __restrict__ Y, int P, int O, int accum,
    int smod, int shift, int ystride, int yoff,
    short* __restrict__ Yb, int bact, int k3)
{
  __shared__ short As[2][4096];
  __shared__ short Bs[2][4096];
  if (gridDim.z > 1) { W += (size_t)blockIdx.z * 262144; yoff += (int)blockIdx.z; }
  const int tid = threadIdx.x;
  const int lane = tid & 63, wid = tid >> 6;
  const int wr = wid >> 1, wc = wid & 1;
  const int bp = blockIdx.x * 64, bo = blockIdx.y * 64;
  f32x4 acc[2][2];
#pragma unroll
  for (int mi = 0; mi < 2; mi++)
#pragma unroll
    for (int ni = 0; ni < 2; ni++) acc[mi][ni] = (f32x4){0.f, 0.f, 0.f, 0.f};

  const int nseg = k3 ? 3 : 1;
  const int niter = nseg * 8;
  bf16x8 rA[2], rB[2];

  auto stage_load = [&](int it) {
    const int seg = it >> 3, k0 = (it & 7) << 6;
    const int sh = k3 ? (seg - 1) : shift;
    const int sm = k3 ? 256 : smod;
    const short* Wseg = W + (size_t)seg * 262144;
#pragma unroll
    for (int c0 = 0; c0 < 2; c0++) {
      const int c = tid + c0 * 256;
      const int row = c >> 3, kc = c & 7;
      const int p = bp + row;
      bf16x8 av = {0, 0, 0, 0, 0, 0, 0, 0};
      bool ok = true;
      if (sm) { const int s = p & (sm - 1); ok = ((unsigned)(s + sh) < (unsigned)sm); }
      if (ok) av = *(const bf16x8*)&A[(size_t)(p + sh) * 512 + k0 + (kc << 3)];
      rA[c0] = av;
      rB[c0] = *(const bf16x8*)&Wseg[(size_t)(bo + row) * 512 + k0 + (kc << 3)];
    }
  };
  auto stage_write = [&](int cb) {
#pragma unroll
    for (int c0 = 0; c0 < 2; c0++) {
      const int c = tid + c0 * 256;
      const int row = c >> 3, kc = c & 7;
      int soff = (row << 6) + (kc << 3); soff ^= (row & 7) << 3;
      *(bf16x8*)&As[cb][soff] = rA[c0];
      *(bf16x8*)&Bs[cb][soff] = rB[c0];
    }
  };

  stage_load(0);
  int cur = 0;
  for (int it = 0; it < niter; ++it) {
    stage_write(cur);
    __syncthreads();
    if (it + 1 < niter) stage_load(it + 1);  // loads fly during MFMA
#pragma unroll
    for (int ks = 0; ks < 2; ks++) {
      bf16x8 af[2], bfr[2];
#pragma unroll
      for (int mi = 0; mi < 2; mi++) {
        const int row = wr * 32 + mi * 16 + (lane & 15);
        int soff = (row << 6) + (ks << 5) + ((lane >> 4) << 3);
        soff ^= (row & 7) << 3;
        af[mi] = *(const bf16x8*)&As[cur][soff];
      }
#pragma unroll
      for (int ni = 0; ni < 2; ni++) {
        const int row = wc * 32 + ni * 16 + (lane & 15);
        int soff = (row << 6) + (ks << 5) + ((lane >> 4) << 3);
        soff ^= (row & 7) << 3;
        bfr[ni] = *(const bf16x8*)&Bs[cur][soff];
      }
#pragma unroll
      for (int mi = 0; mi < 2; mi++)
#pragma unroll
        for (int ni = 0; ni < 2; ni++)
          acc[mi][ni] = __builtin_amdgcn_mfma_f32_16x16x32_bf16(af[mi], bfr[ni], acc[mi][ni], 0, 0, 0);
    }
    cur ^= 1;
  }
#pragma unroll
  for (int mi = 0; mi < 2; mi++)
#pragma unroll
    for (int ni = 0; ni < 2; ni++)
#pragma unroll
      for (int r = 0; r < 4; r++) {
        const int p = bp + wr * 32 + mi * 16 + ((lane >> 4) << 2) + r;
        const int o = bo + wc * 32 + ni * 16 + (lane & 15);
        float v = acc[mi][ni][r];
        if (bias) v += bias[o];
        if (res)  v += res[(size_t)p * O + o];
        const size_t yi = ((size_t)p * ystride + yoff) * O + o;
        if (accum) v += Y[yi];
        if (Y) Y[yi] = v;
        if (Yb) Yb[yi] = f2bf(bact ? eluf(v) : v);
      }
}

// ---------------- bf16 MFMA flash attention, QBLK=128, 512 threads ----
__global__ __launch_bounds__(512) void battn_k(
    const short* __restrict__ qkv, float* __restrict__ Oa,
    short* __restrict__ Ob, int S)
{
  __shared__ short sq[8192];
  __shared__ short sk[4096];
  __shared__ short svt[4096];
  const int tid = threadIdx.x;
  const int lane = tid & 63, w = tid >> 6;
  const int bl = blockIdx.y >> 3, h = blockIdx.y & 7;
  const int q0 = blockIdx.x * 128;
  const short* base = qkv + (size_t)bl * S * 1536 + h * 64;

  {
    const int row = tid >> 2, c0 = (tid & 3) << 4;
    const short* src = base + (size_t)(q0 + row) * 1536 + c0;
    bf16x8 v0 = *(const bf16x8*)&src[0];
    bf16x8 v1 = *(const bf16x8*)&src[8];
#pragma unroll
    for (int e = 0; e < 8; e++) {
      v0[e] = f2bf(bf2f(v0[e]) * 0.125f);
      v1[e] = f2bf(bf2f(v1[e]) * 0.125f);
    }
    int s0 = (row << 6) + c0;       s0 ^= (row & 7) << 3;
    int s1 = (row << 6) + c0 + 8;   s1 ^= (row & 7) << 3;
    *(bf16x8*)&sq[s0] = v0; *(bf16x8*)&sq[s1] = v1;
  }
  __syncthreads();
  bf16x8 af[2];
#pragma unroll
  for (int ks = 0; ks < 2; ks++) {
    const int row = (w << 4) + (lane & 15);
    int soff = (row << 6) + (((lane >> 4) + 4 * ks) << 3);
    soff ^= (row & 7) << 3;
    af[ks] = *(const bf16x8*)&sq[soff];
  }

  f32x4 oacc[4];
#pragma unroll
  for (int dt = 0; dt < 4; dt++) oacc[dt] = (f32x4){0.f, 0.f, 0.f, 0.f};
  float m[4], l[4];
#pragma unroll
  for (int r = 0; r < 4; r++) { m[r] = -INFINITY; l[r] = 0.f; }

  for (int t0 = 0; t0 < S; t0 += 64) {
    __syncthreads();
    if (tid < 256) {
      const int row = tid >> 2, c0 = (tid & 3) << 4;
      const short* ksrc = base + (size_t)(t0 + row) * 1536 + 512 + c0;
      int s0 = (row << 6) + c0;       s0 ^= (row & 7) << 3;
      int s1 = (row << 6) + c0 + 8;   s1 ^= (row & 7) << 3;
      *(bf16x8*)&sk[s0] = *(const bf16x8*)&ksrc[0];
      *(bf16x8*)&sk[s1] = *(const bf16x8*)&ksrc[8];
    } else {
      const int t = tid - 256;
      const int row = t >> 2, c0 = (t & 3) << 4;
      const short* vsrc = base + (size_t)(t0 + row) * 1536 + 1024 + c0;
      const bf16x8 va0 = *(const bf16x8*)&vsrc[0];
      const bf16x8 va1 = *(const bf16x8*)&vsrc[8];
#pragma unroll
      for (int i = 0; i < 16; i++) {
        const int dd = c0 + i;
        int so = (dd << 6) + row;
        so ^= ((dd & 7) ^ (((dd >> 4) & 3) << 1)) << 3;
        svt[so] = (i < 8) ? va0[i & 7] : va1[i & 7];
      }
    }
    __syncthreads();
    f32x4 sacc[4];
#pragma unroll
    for (int ct = 0; ct < 4; ct++) {
      sacc[ct] = (f32x4){0.f, 0.f, 0.f, 0.f};
#pragma unroll
      for (int ks = 0; ks < 2; ks++) {
        const int row = (ct << 4) + (lane & 15);
        int soff = (row << 6) + (((lane >> 4) + 4 * ks) << 3);
        soff ^= (row & 7) << 3;
        const bf16x8 bk = *(const bf16x8*)&sk[soff];
        sacc[ct] = __builtin_amdgcn_mfma_f32_16x16x32_bf16(af[ks], bk, sacc[ct], 0, 0, 0);
      }
    }
    float p[4][4]; float corr[4];
#pragma unroll
    for (int r = 0; r < 4; r++) {
      float mx = fmaxf(fmaxf(sacc[0][r], sacc[1][r]), fmaxf(sacc[2][r], sacc[3][r]));
      mx = fmaxf(mx, __shfl_xor(mx, 1));
      mx = fmaxf(mx, __shfl_xor(mx, 2));
      mx = fmaxf(mx, __shfl_xor(mx, 4));
      mx = fmaxf(mx, __shfl_xor(mx, 8));
      const float newm = fmaxf(m[r], mx);
      corr[r] = expf(m[r] - newm);
      float psum = 0.f;
#pragma unroll
      for (int ct = 0; ct < 4; ct++) { p[ct][r] = expf(sacc[ct][r] - newm); psum += p[ct][r]; }
      psum += __shfl_xor(psum, 1);
      psum += __shfl_xor(psum, 2);
      psum += __shfl_xor(psum, 4);
      psum += __shfl_xor(psum, 8);
      l[r] = l[r] * corr[r] + psum;
      m[r] = newm;
#pragma unroll
      for (int dt = 0; dt < 4; dt++) oacc[dt][r] *= corr[r];
    }
#pragma unroll
    for (int r = 0; r < 4; r++)
#pragma unroll
      for (int ct = 0; ct < 4; ct++) {
        const int q = (w << 4) + ((lane >> 4) << 2) + r;
        const int kv = (ct << 4) + (lane & 15);
        int so = (q << 6) + kv; so ^= (q & 7) << 3;
        sq[so] = f2bf(p[ct][r]);
      }
#pragma unroll
    for (int ks = 0; ks < 2; ks++) {
      const int prow = (w << 4) + (lane & 15);
      int poff = (prow << 6) + (((lane >> 4) + 4 * ks) << 3);
      poff ^= (prow & 7) << 3;
      const bf16x8 pa = *(const bf16x8*)&sq[poff];
#pragma unroll
      for (int dt = 0; dt < 4; dt++) {
        const int vrow = (dt << 4) + (lane & 15);
        int voff = (vrow << 6) + (((lane >> 4) + 4 * ks) << 3);
        voff ^= ((vrow & 7) ^ (((vrow >> 4) & 3) << 1)) << 3;
        const bf16x8 bv = *(const bf16x8*)&svt[voff];
        oacc[dt] = __builtin_amdgcn_mfma_f32_16x16x32_bf16(pa, bv, oacc[dt], 0, 0, 0);
      }
    }
  }
#pragma unroll
  for (int r = 0; r < 4; r++) {
    const float inv = 1.f / l[r];
    const int q = (w << 4) + ((lane >> 4) << 2) + r;
    const size_t rowbase = (size_t)(bl * S + q0 + q) * 512 + h * 64;
#pragma unroll
    for (int dt = 0; dt < 4; dt++) {
      const int d = (dt << 4) + (lane & 15);
      const float ov = oacc[dt][r] * inv;
      if (Oa) Oa[rowbase + d] = ov;
      if (Ob) Ob[rowbase + d] = f2bf(ov);
    }
  }
}

// ---------------- fp32 -> bf16 cast (weights)
__global__ __launch_bounds__(256) void cast_k(const float* __restrict__ src,
    short* __restrict__ dst, int act)
{
  const size_t i = ((size_t)blockIdx.x * 256 + threadIdx.x) * 8;
  float4 a = *(const float4*)&src[i];
  float4 b = *(const float4*)&src[i + 4];
  if (act) {
    a.x = eluf(a.x); a.y = eluf(a.y); a.z = eluf(a.z); a.w = eluf(a.w);
    b.x = eluf(b.x); b.y = eluf(b.y); b.z = eluf(b.z); b.w = eluf(b.w);
  }
  bf16x8 o;
  o[0] = f2bf(a.x); o[1] = f2bf(a.y); o[2] = f2bf(a.z); o[3] = f2bf(a.w);
  o[4] = f2bf(b.x); o[5] = f2bf(b.y); o[6] = f2bf(b.z); o[7] = f2bf(b.w);
  *(bf16x8*)&dst[i] = o;
}

// q2d_w [512 o][512 k][3] -> 3 mats [512][512] bf16
__global__ __launch_bounds__(256) void q2dw_k(const float* __restrict__ src, short* __restrict__ dst)
{
  const int idx = blockIdx.x * 256 + threadIdx.x;
  const int w = idx >> 18, rem = idx & 262143;
  const int o = rem >> 9, k = rem & 511;
  dst[idx] = f2bf(src[(size_t)o * 1536 + k * 3 + w]);
}

// dec_up_w [NF][512 i][512 o][2 k] -> 4 mats [(f*2+k)][512 o][512 i] bf16
__global__ __launch_bounds__(256) void upw_k(const float* __restrict__ src, short* __restrict__ dst)
{
  const int idx = blockIdx.x * 256 + threadIdx.x;
  const int mi = idx >> 18, f = mi >> 1, kq = mi & 1;
  const int rem = idx & 262143;
  const int o = rem >> 9, i2 = rem & 511;
  dst[idx] = f2bf(src[(size_t)f * 524288 + (size_t)i2 * 1024 + o * 2 + kq]);
}

// down weight [512 o][512 i][2 ks] -> fp32 [512 o][ks*512+i]
__global__ __launch_bounds__(256) void downw_k(const float* __restrict__ src, float* __restrict__ dst)
{
  const int idx = blockIdx.x * 256 + threadIdx.x; // 524288
  const int i = idx & 511, ks = (idx >> 9) & 1, o = idx >> 10;
  dst[idx] = src[(size_t)o * 1024 + i * 2 + ks];
}

// e2q_w [512 o][512 k][3 w] -> fp32 [3 w][512 o][512 k]
__global__ __launch_bounds__(256) void e2qw_k(const float* __restrict__ src, float* __restrict__ dst)
{
  const int idx = blockIdx.x * 256 + threadIdx.x; // 786432
  const int w = idx >> 18, rem = idx & 262143;
  const int o = rem >> 9, k = rem & 511;
  dst[idx] = src[(size_t)o * 1536 + k * 3 + w];
}

// codebook [512 d][512 n] -> fp32 cbT [512 n][512 d]
__global__ __launch_bounds__(256) void cbt_k(const float* __restrict__ src, float* __restrict__ dst)
{
  const int idx = blockIdx.x * 256 + threadIdx.x; // 262144
  const int n = idx >> 9, d = idx & 511;
  dst[idx] = src[(size_t)d * 512 + n];
}

// ---------------- layernorm over C=512, optional bf16 out
__global__ __launch_bounds__(256) void ln_k(const float* __restrict__ X,
    const float* __restrict__ g, const float* __restrict__ bta,
    float* __restrict__ Y, short* __restrict__ Ob)
{
  const int row = blockIdx.x * 4 + (threadIdx.x >> 6);
  const int lane = threadIdx.x & 63;
  const float* x = X + (size_t)row * 512;
  float v[8]; float s = 0.f;
#pragma unroll
  for (int i = 0; i < 8; i++) { v[i] = x[lane + i * 64]; s += v[i]; }
#pragma unroll
  for (int off = 1; off < 64; off <<= 1) s += __shfl_xor(s, off);
  const float mean = s * (1.f / 512.f);
  float vs = 0.f;
#pragma unroll
  for (int i = 0; i < 8; i++) { const float d = v[i] - mean; vs += d * d; }
#pragma unroll
  for (int off = 1; off < 64; off <<= 1) vs += __shfl_xor(vs, off);
  const float rstd = 1.f / sqrtf(vs * (1.f / 512.f) + 1e-5f);
  float* y = Y ? (Y + (size_t)row * 512) : nullptr;
#pragma unroll
  for (int i = 0; i < 8; i++) {
    const int c = lane + i * 64;
    const float o = (v[i] - mean) * rstd * g[c] + bta[c];
    if (y) y[c] = o;
    if (Ob) Ob[(size_t)row * 512 + c] = f2bf(o);
  }
}

// ---------------- log_softmax over C=512 -> f32 out
__global__ __launch_bounds__(256) void lsm_k(const float* __restrict__ X,
    float* __restrict__ out)
{
  const int row = blockIdx.x * 4 + (threadIdx.x >> 6);
  const int lane = threadIdx.x & 63;
  const float* x = X + (size_t)row * 512;
  float v[8]; float mx = -3.0e38f;
#pragma unroll
  for (int i = 0; i < 8; i++) { v[i] = x[lane + i * 64]; mx = fmaxf(mx, v[i]); }
#pragma unroll
  for (int off = 1; off < 64; off <<= 1) mx = fmaxf(mx, __shfl_xor(mx, off));
  float sum = 0.f;
#pragma unroll
  for (int i = 0; i < 8; i++) sum += expf(v[i] - mx);
#pragma unroll
  for (int off = 1; off < 64; off <<= 1) sum += __shfl_xor(sum, off);
  const float ls = logf(sum);
  float* y = out + (size_t)row * 512;
#pragma unroll
  for (int i = 0; i < 8; i++) y[lane + i * 64] = v[i] - mx - ls;
}

// ---------------- embedding gather (+bf16 elu copy)
__global__ __launch_bounds__(256) void embed_k(const int* __restrict__ x,
    const float* __restrict__ emb, float* __restrict__ out, short* __restrict__ outb)
{
  const int i = blockIdx.x * 256 + threadIdx.x;
  const int p = i >> 7, c4 = i & 127;
  const int id = x[p];
  const float4 v = *(const float4*)&emb[(size_t)id * 512 + c4 * 4];
  *(float4*)&out[(size_t)p * 512 + c4 * 4] = v;
  short* ob = outb + (size_t)p * 512 + c4 * 4;
  ob[0] = f2bf(eluf(v.x)); ob[1] = f2bf(eluf(v.y));
  ob[2] = f2bf(eluf(v.z)); ob[3] = f2bf(eluf(v.w));
}

// ---------------- codebook column norms from cbT [n][d]
__global__ __launch_bounds__(64) void cnorm_k(const float* __restrict__ cbT, float* __restrict__ cn)
{
  const int n = blockIdx.x; const int lane = threadIdx.x;
  float s = 0.f;
#pragma unroll
  for (int i = 0; i < 8; i++) {
    const float v = cbT[(size_t)n * 512 + lane + i * 64];
    s += v * v;
  }
#pragma unroll
  for (int off = 1; off < 64; off <<= 1) s += __shfl_xor(s, off);
  if (lane == 0) cn[n] = s;
}

// ---------------- VQ argmin
__global__ __launch_bounds__(256) void argmin_k(const float* __restrict__ scores,
    const float* __restrict__ cn, int* __restrict__ ids,
    float* __restrict__ out_ids)
{
  const int row = blockIdx.x * 4 + (threadIdx.x >> 6);
  const int lane = threadIdx.x & 63;
  const float* sr = scores + (size_t)row * 512;
  float best = 3.0e38f; int bi = 0x7fffffff;
#pragma unroll
  for (int i = 0; i < 8; i++) {
    const int n = lane + i * 64;
    const float v = cn[n] - 2.f * sr[n];
    if (v < best || (v == best && n < bi)) { best = v; bi = n; }
  }
#pragma unroll
  for (int off = 1; off < 64; off <<= 1) {
    const float ov = __shfl_xor(best, off);
    const int oi = __shfl_xor(bi, off);
    if (ov < best || (ov == best && oi < bi)) { best = ov; bi = oi; }
  }
  if (lane == 0) { ids[row] = bi; out_ids[row] = (float)bi; }
}

// ---------------- z = z_e + (q - z_e) -> out_z (+bf16); q from cbT
__global__ __launch_bounds__(128) void zq_k(const float* __restrict__ z_e,
    const float* __restrict__ cbT, const int* __restrict__ ids,
    float* __restrict__ zout, short* __restrict__ zb, float* __restrict__ dpart)
{
  __shared__ float red[2];
  const int p = blockIdx.x, t = threadIdx.x;
  const int id = ids[p];
  const float4 ze = *(const float4*)&z_e[(size_t)p * 512 + t * 4];
  const float4 q4 = *(const float4*)&cbT[(size_t)id * 512 + t * 4];
  const float4 dv = make_float4(q4.x - ze.x, q4.y - ze.y, q4.z - ze.z, q4.w - ze.w);
  const float4 z  = make_float4(ze.x + dv.x, ze.y + dv.y, ze.z + dv.z, ze.w + dv.w);
  *(float4*)&zout[(size_t)p * 512 + t * 4] = z;
  short* zo = zb + (size_t)p * 512 + t * 4;
  zo[0] = f2bf(z.x); zo[1] = f2bf(z.y); zo[2] = f2bf(z.z); zo[3] = f2bf(z.w);
  float loc = dv.x * dv.x + dv.y * dv.y + dv.z * dv.z + dv.w * dv.w;
#pragma unroll
  for (int off = 1; off < 64; off <<= 1) loc += __shfl_xor(loc, off);
  const int lane = t & 63, w = t >> 6;
  if (lane == 0) red[w] = loc;
  __syncthreads();
  if (t == 0) dpart[p] = red[0] + red[1];
}

__global__ __launch_bounds__(256) void diffred_k(const float* __restrict__ dpart,
    float* __restrict__ out_diff)
{
  __shared__ float red[4];
  const int t = threadIdx.x;
  float s = 0.f;
#pragma unroll
  for (int i = 0; i < 8; i++) s += dpart[t + i * 256];
#pragma unroll
  for (int off = 1; off < 64; off <<= 1) s += __shfl_xor(s, off);
  if ((t & 63) == 0) red[t >> 6] = s;
  __syncthreads();
  if (t == 0) out_diff[0] = (red[0] + red[1] + red[2] + red[3]) * (1.f / 1048576.f);
}

// =====================================================================
extern "C" void kernel_launch(void* const* d_in, const int* in_sizes, int n_in,
                              void* d_out, int out_size, void* d_ws, size_t ws_size,
                              hipStream_t stream)
{
  const int*   x         = (const int*)d_in[0];
  const float* embed     = (const float*)d_in[1];
  const float* enc_res_w = (const float*)d_in[2];
  const float* enc_res_b = (const float*)d_in[3];
  const float* enc_in_w  = (const float*)d_in[4];
  const float* enc_in_b  = (const float*)d_in[5];
  const float* enc_out_w = (const float*)d_in[6];
  const float* enc_out_b = (const float*)d_in[7];
  const float* enc_ln_g  = (const float*)d_in[8];
  const float* enc_ln_b  = (const float*)d_in[9];
  const float* enc_down_w= (const float*)d_in[10];
  const float* enc_down_b= (const float*)d_in[11];
  const float* e2q_w     = (const float*)d_in[12];
  const float* e2q_b     = (const float*)d_in[13];
  const float* codebook  = (const float*)d_in[14];
  const float* q2d_w     = (const float*)d_in[15];
  const float* q2d_b     = (const float*)d_in[16];
  const float* dec_res_w = (const float*)d_in[17];
  const float* dec_res_b = (const float*)d_in[18];
  const float* dec_in_w  = (const float*)d_in[19];
  const float* dec_in_b  = (const float*)d_in[20];
  const float* dec_out_w = (const float*)d_in[21];
  const float* dec_out_b = (const float*)d_in[22];
  const float* dec_ln_g  = (const float*)d_in[23];
  const float* dec_ln_b  = (const float*)d_in[24];
  const float* dec_up_w  = (const float*)d_in[25];
  const float* dec_up_b  = (const float*)d_in[26];

  float* ws = (float*)d_ws;
  float* S0   = ws;
  float* S1   = ws + SLOT;
  float* S2   = ws + 2 * SLOT;
  float* QKVb = ws + 3 * SLOT;               // scratch region (bf16 QKV + repacks)
  float* cnorm = QKVb + (size_t)8192 * 1536; // [512]
  int*   idsI  = (int*)(cnorm + 512);        // [2048]
  float* dpart = (float*)(idsI + 2048);      // [2048]

  float* out      = (float*)d_out;
  float* out_logp = out;                     // 4194304
  float* out_z    = out + 4194304;           // 1048576
  float* out_diff = out + 5242880;           // 1
  float* out_ids  = out + 5242881;           // 2048

  short* q2dWb   = (short*)out_logp;         // 786432
  short* resWb   = q2dWb + 786432;           // 1572864
  short* inWb    = resWb + 1572864;          // 1572864
  short* outWb   = inWb + 1572864;           // 524288
  short* upWb    = outWb + 524288;           // 1048576
  short* AbA     = upWb + 1048576;           // 2097152
  short* encResWb= AbA + 2097152;            // 786432 (fills logp region)
  short* AbB   = (short*)(QKVb + 8388608);   // decoder ping-pong
  // out_z region (dead until zq_k): enc in/out bf16 W + ds1 fp32 W
  short* encInWb  = (short*)out_z;           // 786432 shorts
  short* encOutWb = encInWb + 786432;        // 262144 shorts
  float* dsW      = out_z + 524288;          // 524288 floats
  // QKV stored bf16 in QKVb front
  short* QKVsh = (short*)QKVb;
  // QKVb-front repacks (dead window after enc attention)
  float* e2qT  = QKVb;                       // 786432
  float* ds2W  = QKVb + 786432;              // 524288
  float* cbT   = QKVb + 1310720;             // 262144
  // encoder bf16 activation ping-pong in QKVb front (dead before QKV output)
  short* E0    = (short*)QKVb;               // 8192*512 shorts
  short* E1    = E0 + 4194304;
  short* S2sh  = (short*)S2;                 // bf16 h / attn out

  // ---- weight conversions + repacks ----
  q2dw_k<<<3072, 256, 0, stream>>>(q2d_w, q2dWb);
  cast_k<<<768, 256, 0, stream>>>(dec_res_w, resWb, 0);
  cast_k<<<768, 256, 0, stream>>>(dec_in_w,  inWb, 0);
  cast_k<<<256, 256, 0, stream>>>(dec_out_w, outWb, 0);
  upw_k<<<4096, 256, 0, stream>>>(dec_up_w, upWb);
  cast_k<<<384, 256, 0, stream>>>(enc_res_w, encResWb, 0);
  cast_k<<<384, 256, 0, stream>>>(enc_in_w,  encInWb, 0);
  cast_k<<<128, 256, 0, stream>>>(enc_out_w, encOutWb, 0);
  downw_k<<<2048, 256, 0, stream>>>(enc_down_w, dsW);

  // ---- encoder: bf16 MFMA resblock/QKV/attn/out-proj (pre-LN, proven) ----
  embed_k<<<4096, 256, 0, stream>>>(x, embed, S0, E0);
  { dim3 g(128, 8);
    bgemm_k<<<g, 256, 0, stream>>>(E0, encResWb,          enc_res_b,        nullptr, nullptr, 8192, 512, 0, 0, 0, 1, 0, E1, 1, 0);
    bgemm_k<<<g, 256, 0, stream>>>(E1, encResWb + 262144, enc_res_b + 512,  nullptr, nullptr, 8192, 512, 0, 0, 0, 1, 0, E0, 1, 0);
    bgemm_k<<<g, 256, 0, stream>>>(E0, encResWb + 524288, enc_res_b + 1024, S0,      S1, 8192, 512, 0, 0, 0, 1, 0, S2sh, 0, 0);
  }
  { dim3 g(128, 24); // QKV reads S2sh (bf16 h), writes bf16 QKVsh
    bgemm_k<<<g, 256, 0, stream>>>(S2sh, encInWb, enc_in_b, nullptr, nullptr, 8192, 1536, 0, 0, 0, 1, 0, QKVsh, 0, 0);
  }
  battn_k<<<dim3(8, 64), 512, 0, stream>>>(QKVsh, nullptr, S2sh, 1024);
  { dim3 g(128, 8); // out-proj: bf16 attn out + res S1 -> S0 fp32
    bgemm_k<<<g, 256, 0, stream>>>(S2sh, encOutWb, enc_out_b, S1, S0, 8192, 512, 0, 0, 0, 1, 0, nullptr, 0, 0);
  }
  // QKVb dead: stage fp32 repacks
  e2qw_k<<<3072, 256, 0, stream>>>(e2q_w, e2qT);
  downw_k<<<2048, 256, 0, stream>>>(enc_down_w + 524288, ds2W);
  cbt_k<<<1024, 256, 0, stream>>>(codebook, cbT);
  cnorm_k<<<512, 64, 0, stream>>>(cbT, cnorm);
  // ---- post-LN z_e path: strictly fp32 (precision firewall) ----
  ln_k<<<2048, 256, 0, stream>>>(S0, enc_ln_g, enc_ln_b, S1, nullptr);
  launch_gemm(stream, S1, dsW, enc_down_b, nullptr, S2, 4096, 1024, 512, 0, 0, 0, 0, 1, 0, 1024);
  launch_gemm(stream, S2, ds2W, enc_down_b + 512, nullptr, S0, 2048, 1024, 512, 0, 0, 0, 0, 1, 0, 1024);
  // e2q: 3-tap split over gridDim.z, partial planes in S1, exact combine -> S2
  { dim3 g(32, 8, 3);
    gemm_k<<<g, 256, 0, stream>>>(S0, e2qT, nullptr, nullptr, S1, 2048, 512, 512, 0, 0, 256, 0, 1, 0, 512);
  }
  e2qc_k<<<1024, 256, 0, stream>>>(S1, e2q_b, S2);
  // ---- VQ (fp32) ----
  launch_gemm(stream, S2, cbT, nullptr, nullptr, S1, 2048, 512, 512, 0, 0, 0, 0, 1, 0, 512);
  argmin_k<<<512, 256, 0, stream>>>(S1, cnorm, idsI, out_ids);
  zq_k<<<2048, 128, 0, stream>>>(S2, cbT, idsI, out_z, AbA, dpart);
  diffred_k<<<1, 256, 0, stream>>>(dpart, out_diff);

  // ---- decoder (bf16 MFMA) ----
  { dim3 g(32, 8);
    bgemm_k<<<g, 256, 0, stream>>>(AbA, q2dWb, q2d_b, nullptr, S1, 2048, 512, 0, 256, 0, 1, 0, AbB, 1, 1);
  }
  // dec block 0 (P=2048, S=256)
  { dim3 g(32, 8); dim3 gq(32, 24); dim3 gu(32, 8, 2);
    bgemm_k<<<g, 256, 0, stream>>>(AbB, resWb,            dec_res_b,        nullptr, S2, 2048, 512, 0, 0, 0, 1, 0, AbA, 1, 0);
    bgemm_k<<<g, 256, 0, stream>>>(AbA, resWb + 262144,   dec_res_b + 512,  nullptr, S0, 2048, 512, 0, 0, 0, 1, 0, AbB, 1, 0);
    bgemm_k<<<g, 256, 0, stream>>>(AbB, resWb + 524288,   dec_res_b + 1024, S1,      S2, 2048, 512, 0, 0, 0, 1, 0, AbA, 0, 0);
    bgemm_k<<<gq, 256, 0, stream>>>(AbA, inWb,            dec_in_b,         nullptr, nullptr, 2048, 1536, 0, 0, 0, 1, 0, QKVsh, 0, 0);
    battn_k<<<dim3(2, 64), 512, 0, stream>>>(QKVsh, nullptr, AbB, 256);
    bgemm_k<<<g, 256, 0, stream>>>(AbB, outWb,            dec_out_b,        S2, S1, 2048, 512, 0, 0, 0, 1, 0, nullptr, 0, 0);
    ln_k<<<512, 256, 0, stream>>>(S1, dec_ln_g, dec_ln_b, S2, AbA);
    bgemm_k<<<gu, 256, 0, stream>>>(AbA, upWb,            dec_up_b, nullptr, S0, 2048, 512, 0, 0, 0, 2, 0, AbB, 1, 0);
  }
  // dec block 1 (P=4096, S=512)
  { dim3 g(64, 8); dim3 gq(64, 24); dim3 gu(64, 8, 2);
    bgemm_k<<<g, 256, 0, stream>>>(AbB, resWb + 786432,   dec_res_b + 1536, nullptr, S1, 4096, 512, 0, 0, 0, 1, 0, AbA, 1, 0);
    bgemm_k<<<g, 256, 0, stream>>>(AbA, resWb + 1048576,  dec_res_b + 2048, nullptr, S2, 4096, 512, 0, 0, 0, 1, 0, AbB, 1, 0);
    bgemm_k<<<g, 256, 0, stream>>>(AbB, resWb + 1310720,  dec_res_b + 2560, S0,      S1, 4096, 512, 0, 0, 0, 1, 0, AbA, 0, 0);
    bgemm_k<<<gq, 256, 0, stream>>>(AbA, inWb + 786432,   dec_in_b + 1536,  nullptr, nullptr, 4096, 1536, 0, 0, 0, 1, 0, QKVsh, 0, 0);
    battn_k<<<dim3(4, 64), 512, 0, stream>>>(QKVsh, nullptr, AbB, 512);
    bgemm_k<<<g, 256, 0, stream>>>(AbB, outWb + 262144,   dec_out_b + 512,  S1, S0, 4096, 512, 0, 0, 0, 1, 0, nullptr, 0, 0);
    ln_k<<<1024, 256, 0, stream>>>(S0, dec_ln_g + 512, dec_ln_b + 512, S1, AbA);
    bgemm_k<<<gu, 256, 0, stream>>>(AbA, upWb + 524288,   dec_up_b + 512, nullptr, S0, 4096, 512, 0, 0, 0, 2, 0, nullptr, 0, 0);
  }
  // ---- log_softmax -> f32 out (overwrites bf16 scratch region) ----
  lsm_k<<<2048, 256, 0, stream>>>(S0, out_logp);
}